// Round 1
// baseline (1936.262 us; speedup 1.0000x reference)
//
#include <hip/hip_runtime.h>
#include <cstdint>

// Problem dims
// N=2048, IN_DIM=128, HID=64, ENC=64, B=64, SEQ=12

// ---------------------------------------------------------------------------
// E1: x1[n,j] = eb1[j] + sum_k h[n,k]*ew1[j,k]   (2048 x 64)
__global__ __launch_bounds__(256) void extract1(
    const float* __restrict__ h, const float* __restrict__ ew1,
    const float* __restrict__ eb1, float* __restrict__ x1)
{
  int idx = blockIdx.x * 256 + threadIdx.x;   // 131072 total
  int n = idx >> 6, j = idx & 63;
  const float4* hr = (const float4*)(h + (size_t)n * 128);
  const float4* wr = (const float4*)(ew1 + (size_t)j * 128);
  float acc = eb1[j];
#pragma unroll
  for (int k4 = 0; k4 < 32; ++k4) {
    float4 a = hr[k4], w = wr[k4];
    acc += a.x * w.x + a.y * w.y + a.z * w.z + a.w * w.w;
  }
  x1[idx] = acc;
}

// ---------------------------------------------------------------------------
// E2: pooled = adj @ x1, deg = rowsum(adj); x2 = pooled/deg + eps1*x1
// block = 16 rows, 256 threads
__global__ __launch_bounds__(256) void extract2(
    const float* __restrict__ adj, const float* __restrict__ x1,
    const float* __restrict__ eps1, float* __restrict__ x2)
{
  const int n0 = blockIdx.x * 16;
  const int t = threadIdx.x;
  __shared__ float adj_l[16][256];   // 16KB
  __shared__ float x1_l[256][64];    // 64KB
  __shared__ float deg_l[16];
  if (t < 16) deg_l[t] = 0.f;
  __syncthreads();
  const int j = t & 63, rg = t >> 6;   // 4 row-groups of 4 rows each
  float acc[4] = {0.f, 0.f, 0.f, 0.f};
  for (int kc = 0; kc < 2048; kc += 256) {
    // stage adj rows (16 x 256)
    for (int f4 = t; f4 < 16 * 64; f4 += 256) {
      int r = f4 >> 6, q = f4 & 63;
      *(float4*)&adj_l[r][q * 4] =
          *(const float4*)&adj[(size_t)(n0 + r) * 2048 + kc + q * 4];
    }
    // stage x1 chunk (256 x 64)
    for (int f4 = t; f4 < 256 * 16; f4 += 256) {
      int kk = f4 >> 4, q = f4 & 15;
      *(float4*)&x1_l[kk][q * 4] =
          *(const float4*)&x1[(size_t)(kc + kk) * 64 + q * 4];
    }
    __syncthreads();
    // deg partials: 16 threads per row
    {
      int r = t >> 4, l16 = t & 15;
      float p = 0.f;
      for (int kk = l16; kk < 256; kk += 16) p += adj_l[r][kk];
      for (int s = 8; s; s >>= 1) p += __shfl_down(p, s, 16);
      if (l16 == 0) deg_l[r] += p;
    }
    // pooled partials
    for (int kk = 0; kk < 256; ++kk) {
      float xv = x1_l[kk][j];
#pragma unroll
      for (int rr = 0; rr < 4; ++rr) acc[rr] += adj_l[rg * 4 + rr][kk] * xv;
    }
    __syncthreads();
  }
  const float ep = eps1[0];
#pragma unroll
  for (int rr = 0; rr < 4; ++rr) {
    int r = rg * 4 + rr;
    float d = deg_l[r];
    d = (d < 1e-6f) ? 1.f : d;
    size_t off = (size_t)(n0 + r) * 64 + j;
    x2[off] = acc[rr] / d + ep * x1[off];
  }
}

// ---------------------------------------------------------------------------
// E3: BN stats over axis 0 -> scale[j] = rstd*bnw, shift[j] = bnb - mean*rstd*bnw
__global__ __launch_bounds__(256) void extract3(
    const float* __restrict__ x2, const float* __restrict__ bnw,
    const float* __restrict__ bnb, float* __restrict__ scale,
    float* __restrict__ shift)
{
  __shared__ float sl[4][64], ql[4][64];
  int t = threadIdx.x, j = t & 63, rg = t >> 6;
  float s = 0.f, q = 0.f;
  for (int r = rg; r < 2048; r += 4) {
    float v = x2[(size_t)r * 64 + j];
    s += v; q += v * v;
  }
  sl[rg][j] = s; ql[rg][j] = q;
  __syncthreads();
  if (t < 64) {
    float ss = sl[0][t] + sl[1][t] + sl[2][t] + sl[3][t];
    float qq = ql[0][t] + ql[1][t] + ql[2][t] + ql[3][t];
    float mean = ss * (1.f / 2048.f);
    float var = qq * (1.f / 2048.f) - mean * mean;
    float rstd = rsqrtf(var + 1e-5f);
    float sc = rstd * bnw[t];
    scale[t] = sc;
    shift[t] = bnb[t] - mean * sc;
  }
}

// ---------------------------------------------------------------------------
// E4: xn = x2*scale+shift; feat = xn@ew2.T+eb2; fp = feat@wg+bg;
//     fpl[n,o] = wl_b[o] + sum_e fp[n,e]*wl_w[o,64+e]
// block = 4 nodes x 64
__global__ __launch_bounds__(256) void extract4(
    const float* __restrict__ x2, const float* __restrict__ scale,
    const float* __restrict__ shift, const float* __restrict__ ew2,
    const float* __restrict__ eb2, const float* __restrict__ wg,
    const float* __restrict__ bg, const float* __restrict__ wl_w,
    const float* __restrict__ wl_b, float* __restrict__ fpl)
{
  __shared__ float xn[4][64], ft[4][64], fp[4][64];
  int t = threadIdx.x, sub = t >> 6, o = t & 63;
  int n = blockIdx.x * 4 + sub;
  xn[sub][o] = x2[(size_t)n * 64 + o] * scale[o] + shift[o];
  __syncthreads();
  {
    float acc = eb2[o];
    for (int k = 0; k < 64; ++k) acc += xn[sub][k] * ew2[o * 64 + k];
    ft[sub][o] = acc;
  }
  __syncthreads();
  {
    float acc = bg[0];
    for (int k = 0; k < 64; ++k) acc += ft[sub][k] * wg[k * 64 + o];
    fp[sub][o] = acc;
  }
  __syncthreads();
  {
    float acc = wl_b[o];
    for (int k = 0; k < 64; ++k) acc += fp[sub][k] * wl_w[o * 128 + 64 + k];
    fpl[(size_t)n * 64 + o] = acc;
  }
}

// ---------------------------------------------------------------------------
// wlT[h*64+o] = wl_w[o*128+h]  (first 64 input-cols of wl_w, transposed)
__global__ __launch_bounds__(256) void transpose_wl(
    const float* __restrict__ wl_w, float* __restrict__ wlT)
{
  int idx = blockIdx.x * 256 + threadIdx.x;   // 4096
  int hh = idx >> 6, o = idx & 63;
  wlT[idx] = wl_w[o * 128 + hh];
}

// ---------------------------------------------------------------------------
// One GRU step, fused. Block: batch b (blockIdx.y), nodes [a, a+64).
// Split semantics: node n uses ru of node n>>1 (r) and 1024+(n>>1) (u)
// at gate offset ((n&1)<<6)+h.
__global__ __launch_bounds__(256) void gru_step(
    const float* __restrict__ hs_in, float* __restrict__ hs_out,
    const float* __restrict__ inputs, int tstep, int first,
    const float* __restrict__ w1, const float* __restrict__ b1,
    const float* __restrict__ w2, const float* __restrict__ b2,
    const float* __restrict__ fpl, const float* __restrict__ wlT)
{
  const int b = blockIdx.y;
  const int a = blockIdx.x * 64;    // own node range [a, a+64)
  const int t = threadIdx.x;
  const int halfBase = a >> 1;      // r-src nodes [halfBase,+32); u-src [1024+halfBase,+32)

  __shared__ float hs_src[64][64];  // 16KB: hs rows of the 64 src nodes
  __shared__ float ru[64][128];     // 32KB: rows 0..31 r-src, rows 32..63 u-src
  __shared__ float xt_src[64];
  __shared__ float xt_own[64];
  float* ruf = (float*)ru;

  const float* xt = inputs + (size_t)(b * 12 + tstep) * 2048;
  const float* hsb = hs_in + (size_t)b * 2048 * 64;

  if (t < 64) {
    xt_own[t] = xt[a + t];
  } else if (t < 128) {
    int sl = t - 64;
    int m = (sl < 32) ? (halfBase + sl) : (1024 + halfBase + sl - 32);
    xt_src[sl] = xt[m];
  }
  if (first) {
    for (int i = t; i < 4096; i += 256) ((float*)hs_src)[i] = 0.f;
  } else {
    for (int f4 = t; f4 < 1024; f4 += 256) {
      int sl = f4 >> 4, q = f4 & 15;
      int m = (sl < 32) ? (halfBase + sl) : (1024 + halfBase + sl - 32);
      *(float4*)&hs_src[sl][q * 4] = *(const float4*)&hsb[(size_t)m * 64 + q * 4];
    }
  }
  __syncthreads();

  float wcol[65];

  // ---- Phase 1: ru = sigmoid([xt, hs] @ w1 + b1) for the 64 src nodes
  {
    const int j2 = t & 127, mg = t >> 7;
#pragma unroll
    for (int i = 0; i < 65; ++i) wcol[i] = w1[i * 128 + j2];
    const float bb = b1[j2];
    for (int ml = mg * 32; ml < mg * 32 + 32; ++ml) {
      float acc = bb + xt_src[ml] * wcol[0];
#pragma unroll
      for (int h4 = 0; h4 < 16; ++h4) {
        float4 hv = *(float4*)&hs_src[ml][h4 * 4];
        acc += hv.x * wcol[h4 * 4 + 1] + hv.y * wcol[h4 * 4 + 2]
             + hv.z * wcol[h4 * 4 + 3] + hv.w * wcol[h4 * 4 + 4];
      }
      ru[ml][j2] = 1.f / (1.f + __expf(-acc));
    }
  }
  __syncthreads();

  // ---- Phase 2a: rh in place over rows 0..31: ru[ml][j] *= hs[consumer node]
  for (int idx = t; idx < 4096; idx += 256) {
    int ml = idx >> 7, j = idx & 127;
    int n = a + 2 * ml + (j >> 6);
    int hh = j & 63;
    float hsv = first ? 0.f : hsb[(size_t)n * 64 + hh];
    ruf[idx] *= hsv;
  }
  __syncthreads();

  // ---- Phase 2b: c = tanh([xt, rh] @ w2 + b2)
  const int o = t & 63, ng = t >> 6;
  float c_reg[16];
  {
#pragma unroll
    for (int i = 0; i < 65; ++i) wcol[i] = w2[i * 64 + o];
    const float bb = b2[o];
#pragma unroll
    for (int q = 0; q < 16; ++q) {
      int nl = ng * 16 + q;
      int row = nl >> 1, base = (nl & 1) << 6;
      float acc = bb + xt_own[nl] * wcol[0];
#pragma unroll
      for (int h4 = 0; h4 < 16; ++h4) {
        float4 rv = *(float4*)&ru[row][base + h4 * 4];
        acc += rv.x * wcol[h4 * 4 + 1] + rv.y * wcol[h4 * 4 + 2]
             + rv.z * wcol[h4 * 4 + 3] + rv.w * wcol[h4 * 4 + 4];
      }
      float e = __expf(2.f * acc);
      c_reg[q] = 1.f - 2.f / (e + 1.f);  // tanh(acc)
    }
  }
  __syncthreads();
  // write c over the (now dead) rh region, viewed as c[64][64] flat
#pragma unroll
  for (int q = 0; q < 16; ++q) {
    int nl = ng * 16 + q;
    ruf[nl * 64 + o] = c_reg[q];
  }
  __syncthreads();

  // ---- Phase 3a: new = u*hs + (1-u)*c, in place over the c region
  for (int idx = t; idx < 4096; idx += 256) {
    int nl = idx >> 6, hh = idx & 63;
    float u = ru[32 + (nl >> 1)][((nl & 1) << 6) + hh];
    float hsv = first ? 0.f : hsb[(size_t)(a + nl) * 64 + hh];
    ruf[idx] = u * hsv + (1.f - u) * ruf[idx];
  }
  __syncthreads();

  // ---- Phase 3b: out = fpl + new @ wlT   (fpl already includes wl_b + feat part)
  {
#pragma unroll
    for (int i = 0; i < 64; ++i) wcol[i] = wlT[i * 64 + o];
#pragma unroll
    for (int q = 0; q < 16; ++q) {
      int nl = ng * 16 + q;
      float acc = fpl[(size_t)(a + nl) * 64 + o];
#pragma unroll
      for (int h4 = 0; h4 < 16; ++h4) {
        float4 nv = *(float4*)&ruf[nl * 64 + h4 * 4];
        acc += nv.x * wcol[h4 * 4] + nv.y * wcol[h4 * 4 + 1]
             + nv.z * wcol[h4 * 4 + 2] + nv.w * wcol[h4 * 4 + 3];
      }
      hs_out[(size_t)b * 131072 + (size_t)(a + nl) * 64 + o] = acc;
    }
  }
}

// ---------------------------------------------------------------------------
extern "C" void kernel_launch(void* const* d_in, const int* in_sizes, int n_in,
                              void* d_out, int out_size, void* d_ws, size_t ws_size,
                              hipStream_t stream) {
  const float* h      = (const float*)d_in[0];
  const float* adj    = (const float*)d_in[1];
  const float* inputs = (const float*)d_in[2];
  const float* ew1    = (const float*)d_in[3];
  const float* eb1    = (const float*)d_in[4];
  const float* ew2    = (const float*)d_in[5];
  const float* eb2    = (const float*)d_in[6];
  const float* eps1   = (const float*)d_in[7];
  const float* bnw    = (const float*)d_in[8];
  const float* bnb    = (const float*)d_in[9];
  const float* w1     = (const float*)d_in[10];
  const float* b1     = (const float*)d_in[11];
  const float* w2     = (const float*)d_in[12];
  const float* b2     = (const float*)d_in[13];
  const float* wg     = (const float*)d_in[14];
  const float* bg     = (const float*)d_in[15];
  const float* wl_w   = (const float*)d_in[16];
  const float* wl_b   = (const float*)d_in[17];

  float* out = (float*)d_out;
  float* ws  = (float*)d_ws;

  // ws layout (floats):
  //   [0 .. 8388607]  hs ping buffer (aliased by x1/x2 during extractor phase)
  //   [8388608 ..]    fpl (131072), wlT (4096), scale (64), shift (64)
  float* hs_ws = ws;
  float* x1    = ws;                 // alias: used only before first gru_step
  float* x2    = ws + 131072;        // alias: ditto
  float* fpl   = ws + 8388608;
  float* wlT   = fpl + 131072;
  float* scale = wlT + 4096;
  float* shift = scale + 64;

  extract1<<<512, 256, 0, stream>>>(h, ew1, eb1, x1);
  extract2<<<128, 256, 0, stream>>>(adj, x1, eps1, x2);
  extract3<<<1, 256, 0, stream>>>(x2, bnw, bnb, scale, shift);
  extract4<<<512, 256, 0, stream>>>(x2, scale, shift, ew2, eb2, wg, bg,
                                    wl_w, wl_b, fpl);
  transpose_wl<<<16, 256, 0, stream>>>(wl_w, wlT);

  dim3 grid(32, 64);
  for (int t = 0; t < 12; ++t) {
    // even t -> write ws, odd t -> write out; t=11 (last) lands in d_out
    float* obuf = (t & 1) ? out : hs_ws;
    const float* ibuf = (t & 1) ? hs_ws : out;   // t=0 ignores ibuf (first=1)
    gru_step<<<grid, 256, 0, stream>>>(ibuf, obuf, inputs, t, (t == 0) ? 1 : 0,
                                       w1, b1, w2, b2, fpl, wlT);
  }
}

// Round 2
// 1327.286 us; speedup vs baseline: 1.4588x; 1.4588x over previous
//
#include <hip/hip_runtime.h>
#include <cstdint>

// Problem dims: N=2048, IN_DIM=128, HID=64, ENC=64, B=64, SEQ=12

// ---------------------------------------------------------------------------
// E1: x1[n,j] = eb1[j] + sum_k h[n,k]*ew1[j,k]   (2048 x 64)
__global__ __launch_bounds__(256) void extract1(
    const float* __restrict__ h, const float* __restrict__ ew1,
    const float* __restrict__ eb1, float* __restrict__ x1)
{
  int idx = blockIdx.x * 256 + threadIdx.x;   // 131072 total
  int n = idx >> 6, j = idx & 63;
  const float4* hr = (const float4*)(h + (size_t)n * 128);
  const float4* wr = (const float4*)(ew1 + (size_t)j * 128);
  float acc = eb1[j];
#pragma unroll
  for (int k4 = 0; k4 < 32; ++k4) {
    float4 a = hr[k4], w = wr[k4];
    acc += a.x * w.x + a.y * w.y + a.z * w.z + a.w * w.w;
  }
  x1[idx] = acc;
}

// ---------------------------------------------------------------------------
// E2: pooled = adj @ x1, deg = rowsum(adj); x2 = pooled/deg + eps1*x1
__global__ __launch_bounds__(256) void extract2(
    const float* __restrict__ adj, const float* __restrict__ x1,
    const float* __restrict__ eps1, float* __restrict__ x2)
{
  const int n0 = blockIdx.x * 16;
  const int t = threadIdx.x;
  __shared__ float adj_l[16][256];   // 16KB
  __shared__ float x1_l[256][64];    // 64KB
  __shared__ float deg_l[16];
  if (t < 16) deg_l[t] = 0.f;
  __syncthreads();
  const int j = t & 63, rg = t >> 6;   // 4 row-groups of 4 rows each
  float acc[4] = {0.f, 0.f, 0.f, 0.f};
  for (int kc = 0; kc < 2048; kc += 256) {
    for (int f4 = t; f4 < 16 * 64; f4 += 256) {
      int r = f4 >> 6, q = f4 & 63;
      *(float4*)&adj_l[r][q * 4] =
          *(const float4*)&adj[(size_t)(n0 + r) * 2048 + kc + q * 4];
    }
    for (int f4 = t; f4 < 256 * 16; f4 += 256) {
      int kk = f4 >> 4, q = f4 & 15;
      *(float4*)&x1_l[kk][q * 4] =
          *(const float4*)&x1[(size_t)(kc + kk) * 64 + q * 4];
    }
    __syncthreads();
    {
      int r = t >> 4, l16 = t & 15;
      float p = 0.f;
      for (int kk = l16; kk < 256; kk += 16) p += adj_l[r][kk];
      for (int s = 8; s; s >>= 1) p += __shfl_down(p, s, 16);
      if (l16 == 0) deg_l[r] += p;
    }
    for (int kk = 0; kk < 256; ++kk) {
      float xv = x1_l[kk][j];
#pragma unroll
      for (int rr = 0; rr < 4; ++rr) acc[rr] += adj_l[rg * 4 + rr][kk] * xv;
    }
    __syncthreads();
  }
  const float ep = eps1[0];
#pragma unroll
  for (int rr = 0; rr < 4; ++rr) {
    int r = rg * 4 + rr;
    float d = deg_l[r];
    d = (d < 1e-6f) ? 1.f : d;
    size_t off = (size_t)(n0 + r) * 64 + j;
    x2[off] = acc[rr] / d + ep * x1[off];
  }
}

// ---------------------------------------------------------------------------
// E3: BN stats -> scale/shift
__global__ __launch_bounds__(256) void extract3(
    const float* __restrict__ x2, const float* __restrict__ bnw,
    const float* __restrict__ bnb, float* __restrict__ scale,
    float* __restrict__ shift)
{
  __shared__ float sl[4][64], ql[4][64];
  int t = threadIdx.x, j = t & 63, rg = t >> 6;
  float s = 0.f, q = 0.f;
  for (int r = rg; r < 2048; r += 4) {
    float v = x2[(size_t)r * 64 + j];
    s += v; q += v * v;
  }
  sl[rg][j] = s; ql[rg][j] = q;
  __syncthreads();
  if (t < 64) {
    float ss = sl[0][t] + sl[1][t] + sl[2][t] + sl[3][t];
    float qq = ql[0][t] + ql[1][t] + ql[2][t] + ql[3][t];
    float mean = ss * (1.f / 2048.f);
    float var = qq * (1.f / 2048.f) - mean * mean;
    float rstd = rsqrtf(var + 1e-5f);
    float sc = rstd * bnw[t];
    scale[t] = sc;
    shift[t] = bnb[t] - mean * sc;
  }
}

// ---------------------------------------------------------------------------
// E4: xn = x2*scale+shift; feat = xn@ew2.T+eb2; fp = feat@wg+bg;
//     fpl[n,o] = wl_b[o] + sum_e fp[n,e]*wl_w[o,64+e]
__global__ __launch_bounds__(256) void extract4(
    const float* __restrict__ x2, const float* __restrict__ scale,
    const float* __restrict__ shift, const float* __restrict__ ew2,
    const float* __restrict__ eb2, const float* __restrict__ wg,
    const float* __restrict__ bg, const float* __restrict__ wl_w,
    const float* __restrict__ wl_b, float* __restrict__ fpl)
{
  __shared__ float xn[4][64], ft[4][64], fp[4][64];
  int t = threadIdx.x, sub = t >> 6, o = t & 63;
  int n = blockIdx.x * 4 + sub;
  xn[sub][o] = x2[(size_t)n * 64 + o] * scale[o] + shift[o];
  __syncthreads();
  {
    float acc = eb2[o];
    for (int k = 0; k < 64; ++k) acc += xn[sub][k] * ew2[o * 64 + k];
    ft[sub][o] = acc;
  }
  __syncthreads();
  {
    float acc = bg[0];
    for (int k = 0; k < 64; ++k) acc += ft[sub][k] * wg[k * 64 + o];
    fp[sub][o] = acc;
  }
  __syncthreads();
  {
    float acc = wl_b[o];
    for (int k = 0; k < 64; ++k) acc += fp[sub][k] * wl_w[o * 128 + 64 + k];
    fpl[(size_t)n * 64 + o] = acc;
  }
}

// ---------------------------------------------------------------------------
__global__ __launch_bounds__(256) void transpose_wl(
    const float* __restrict__ wl_w, float* __restrict__ wlT)
{
  int idx = blockIdx.x * 256 + threadIdx.x;   // 4096
  int hh = idx >> 6, o = idx & 63;
  wlT[idx] = wl_w[o * 128 + hh];
}

// ---------------------------------------------------------------------------
// One GRU step, register-tiled GEMMs.
// Block: batch b (blockIdx.y), nodes [a, a+64). 256 threads = 16 tx x 16 ty.
// Split semantics: node n uses ru of row (n-a)>>1 (r) and 32+((n-a)>>1) (u)
// at gate offset ((n&1)<<6)+h.
__global__ __launch_bounds__(256, 3) void gru_step(
    const float* __restrict__ hs_in, float* __restrict__ hs_out,
    const float* __restrict__ inputs, int tstep, int first,
    const float* __restrict__ w1, const float* __restrict__ b1,
    const float* __restrict__ w2, const float* __restrict__ b2,
    const float* __restrict__ fpl, const float* __restrict__ wlT)
{
  const int b = blockIdx.y;
  const int a = blockIdx.x * 64;
  const int t = threadIdx.x;
  const int tx = t & 15, ty = t >> 4;
  const int halfBase = a >> 1;

  // T: transposed activation staging, aliased: hsT -> rhT -> newT
  __shared__ __align__(16) float T[65][68];     // 17.7KB (pad 68: 16B rows, low write conflicts)
  __shared__ __align__(16) float ru[64][128];   // 32KB

  const float* xt  = inputs + (size_t)(b * 12 + tstep) * 2048;
  const float* hsb = hs_in + (size_t)b * 131072;

  // ---- build srcT: T[0][m]=xt_src[m], T[h+1][m]=hs_src[m][h]
  if (t < 64) {
    int m = t;
    int ns = (m < 32) ? (halfBase + m) : (1024 + halfBase + m - 32);
    T[0][m] = xt[ns];
  }
  if (first) {
    for (int i = t; i < 4096; i += 256) T[(i >> 6) + 1][i & 63] = 0.f;
  } else {
    for (int i = t; i < 4096; i += 256) {
      int m = i >> 6, hh = i & 63;
      int ns = (m < 32) ? (halfBase + m) : (1024 + halfBase + m - 32);
      T[hh + 1][m] = hsb[(size_t)ns * 64 + hh];
    }
  }
  __syncthreads();

  const int j0 = tx * 8, m0 = ty * 4;

  // ---- Phase 1 GEMM: ru[m][j] = sigmoid(b1[j] + sum_k T[k][m]*w1[k][j])
  {
    float acc[4][8];
    float4 b0 = *(const float4*)&b1[j0];
    float4 b4 = *(const float4*)&b1[j0 + 4];
    float bj[8] = {b0.x, b0.y, b0.z, b0.w, b4.x, b4.y, b4.z, b4.w};
    {
      float4 hv = *(float4*)&T[0][m0];
      float hvv[4] = {hv.x, hv.y, hv.z, hv.w};
      float4 wa = *(const float4*)&w1[j0];
      float4 wb = *(const float4*)&w1[j0 + 4];
      float wv[8] = {wa.x, wa.y, wa.z, wa.w, wb.x, wb.y, wb.z, wb.w};
#pragma unroll
      for (int i = 0; i < 4; ++i)
#pragma unroll
        for (int j = 0; j < 8; ++j)
          acc[i][j] = bj[j] + hvv[i] * wv[j];
    }
#pragma unroll 4
    for (int k = 1; k <= 64; ++k) {
      float4 hv = *(float4*)&T[k][m0];
      float hvv[4] = {hv.x, hv.y, hv.z, hv.w};
      float4 wa = *(const float4*)&w1[k * 128 + j0];
      float4 wb = *(const float4*)&w1[k * 128 + j0 + 4];
      float wv[8] = {wa.x, wa.y, wa.z, wa.w, wb.x, wb.y, wb.z, wb.w};
#pragma unroll
      for (int i = 0; i < 4; ++i)
#pragma unroll
        for (int j = 0; j < 8; ++j)
          acc[i][j] += hvv[i] * wv[j];
    }
#pragma unroll
    for (int i = 0; i < 4; ++i) {
      float4 s0, s1;
      s0.x = 1.f / (1.f + __expf(-acc[i][0]));
      s0.y = 1.f / (1.f + __expf(-acc[i][1]));
      s0.z = 1.f / (1.f + __expf(-acc[i][2]));
      s0.w = 1.f / (1.f + __expf(-acc[i][3]));
      s1.x = 1.f / (1.f + __expf(-acc[i][4]));
      s1.y = 1.f / (1.f + __expf(-acc[i][5]));
      s1.z = 1.f / (1.f + __expf(-acc[i][6]));
      s1.w = 1.f / (1.f + __expf(-acc[i][7]));
      *(float4*)&ru[m0 + i][j0] = s0;
      *(float4*)&ru[m0 + i][j0 + 4] = s1;
    }
  }
  __syncthreads();

  // ---- Phase 2a: rhT: T[0][n]=xt_own[n], T[h+1][n] = r[n][h]*hs_own[n][h]
  if (t < 64) T[0][t] = xt[a + t];
  for (int i = t; i < 4096; i += 256) {
    int n = i >> 6, hh = i & 63;
    float hsv = first ? 0.f : hsb[(size_t)(a + n) * 64 + hh];
    T[hh + 1][n] = ru[n >> 1][((n & 1) << 6) + hh] * hsv;
  }
  __syncthreads();

  // ---- Phase 2b GEMM: c[m][o] = tanh(b2[o] + sum_k T[k][m]*w2[k][o])
  const int o0 = tx * 4;
  float c[4][4];
  {
    float acc2[4][4];
    float4 bv = *(const float4*)&b2[o0];
    float bb[4] = {bv.x, bv.y, bv.z, bv.w};
    {
      float4 hv = *(float4*)&T[0][m0];
      float hvv[4] = {hv.x, hv.y, hv.z, hv.w};
      float4 wv4 = *(const float4*)&w2[o0];
      float wv[4] = {wv4.x, wv4.y, wv4.z, wv4.w};
#pragma unroll
      for (int i = 0; i < 4; ++i)
#pragma unroll
        for (int j = 0; j < 4; ++j)
          acc2[i][j] = bb[j] + hvv[i] * wv[j];
    }
#pragma unroll 4
    for (int k = 1; k <= 64; ++k) {
      float4 hv = *(float4*)&T[k][m0];
      float hvv[4] = {hv.x, hv.y, hv.z, hv.w};
      float4 wv4 = *(const float4*)&w2[k * 64 + o0];
      float wv[4] = {wv4.x, wv4.y, wv4.z, wv4.w};
#pragma unroll
      for (int i = 0; i < 4; ++i)
#pragma unroll
        for (int j = 0; j < 4; ++j)
          acc2[i][j] += hvv[i] * wv[j];
    }
#pragma unroll
    for (int i = 0; i < 4; ++i)
#pragma unroll
      for (int j = 0; j < 4; ++j) {
        float e = __expf(2.f * acc2[i][j]);
        c[i][j] = 1.f - 2.f / (e + 1.f);   // tanh
      }
  }
  __syncthreads();   // all reads of rhT done before overwriting as newT

  // ---- Phase 3a: newT: T[h][n] = u*hs_own + (1-u)*c
#pragma unroll
  for (int i = 0; i < 4; ++i)
#pragma unroll
    for (int j = 0; j < 4; ++j) {
      int n = m0 + i, hh = o0 + j;
      float u = ru[32 + (n >> 1)][((n & 1) << 6) + hh];
      float hsv = first ? 0.f : hsb[(size_t)(a + n) * 64 + hh];
      T[hh][n] = u * hsv + (1.f - u) * c[i][j];
    }
  __syncthreads();

  // ---- Phase 3b GEMM: out[m][o] = fpl[m][o] + sum_h T[h][m]*wlT[h][o]
  {
    float acc3[4][4];
#pragma unroll
    for (int i = 0; i < 4; ++i) {
      float4 f4 = *(const float4*)&fpl[(size_t)(a + m0 + i) * 64 + o0];
      acc3[i][0] = f4.x; acc3[i][1] = f4.y; acc3[i][2] = f4.z; acc3[i][3] = f4.w;
    }
#pragma unroll 4
    for (int k = 0; k < 64; ++k) {
      float4 hv = *(float4*)&T[k][m0];
      float hvv[4] = {hv.x, hv.y, hv.z, hv.w};
      float4 wv4 = *(const float4*)&wlT[k * 64 + o0];
      float wv[4] = {wv4.x, wv4.y, wv4.z, wv4.w};
#pragma unroll
      for (int i = 0; i < 4; ++i)
#pragma unroll
        for (int j = 0; j < 4; ++j)
          acc3[i][j] += hvv[i] * wv[j];
    }
#pragma unroll
    for (int i = 0; i < 4; ++i) {
      *(float4*)&hs_out[(size_t)b * 131072 + (size_t)(a + m0 + i) * 64 + o0]
        = make_float4(acc3[i][0], acc3[i][1], acc3[i][2], acc3[i][3]);
    }
  }
}

// ---------------------------------------------------------------------------
extern "C" void kernel_launch(void* const* d_in, const int* in_sizes, int n_in,
                              void* d_out, int out_size, void* d_ws, size_t ws_size,
                              hipStream_t stream) {
  const float* h      = (const float*)d_in[0];
  const float* adj    = (const float*)d_in[1];
  const float* inputs = (const float*)d_in[2];
  const float* ew1    = (const float*)d_in[3];
  const float* eb1    = (const float*)d_in[4];
  const float* ew2    = (const float*)d_in[5];
  const float* eb2    = (const float*)d_in[6];
  const float* eps1   = (const float*)d_in[7];
  const float* bnw    = (const float*)d_in[8];
  const float* bnb    = (const float*)d_in[9];
  const float* w1     = (const float*)d_in[10];
  const float* b1     = (const float*)d_in[11];
  const float* w2     = (const float*)d_in[12];
  const float* b2     = (const float*)d_in[13];
  const float* wg     = (const float*)d_in[14];
  const float* bg     = (const float*)d_in[15];
  const float* wl_w   = (const float*)d_in[16];
  const float* wl_b   = (const float*)d_in[17];

  float* out = (float*)d_out;
  float* ws  = (float*)d_ws;

  float* hs_ws = ws;
  float* x1    = ws;                 // alias: used only before first gru_step
  float* x2    = ws + 131072;        // alias: ditto
  float* fpl   = ws + 8388608;
  float* wlT   = fpl + 131072;
  float* scale = wlT + 4096;
  float* shift = scale + 64;

  extract1<<<512, 256, 0, stream>>>(h, ew1, eb1, x1);
  extract2<<<128, 256, 0, stream>>>(adj, x1, eps1, x2);
  extract3<<<1, 256, 0, stream>>>(x2, bnw, bnb, scale, shift);
  extract4<<<512, 256, 0, stream>>>(x2, scale, shift, ew2, eb2, wg, bg,
                                    wl_w, wl_b, fpl);
  transpose_wl<<<16, 256, 0, stream>>>(wl_w, wlT);

  dim3 grid(32, 64);
  for (int t = 0; t < 12; ++t) {
    float* obuf = (t & 1) ? out : hs_ws;
    const float* ibuf = (t & 1) ? hs_ws : out;   // t=0 ignores ibuf (first=1)
    gru_step<<<grid, 256, 0, stream>>>(ibuf, obuf, inputs, t, (t == 0) ? 1 : 0,
                                       w1, b1, w2, b2, fpl, wlT);
  }
}

// Round 3
// 461.437 us; speedup vs baseline: 4.1962x; 2.8764x over previous
//
#include <hip/hip_runtime.h>
#include <cstdint>

// Problem dims: N=2048, IN_DIM=128, HID=64, ENC=64, B=64, SEQ=12

typedef _Float16 half8 __attribute__((ext_vector_type(8)));
typedef float f32x4 __attribute__((ext_vector_type(4)));

static __device__ inline f32x4 mfma16(half8 a, half8 b, f32x4 c) {
  return __builtin_amdgcn_mfma_f32_16x16x32_f16(a, b, c, 0, 0, 0);
}

// ru LDS addressing: fp16 [64 rows][128 cols], XOR-swizzled at 8-half granularity
// so stride-128B column reads spread across banks. Index in half units.
static __device__ inline int ru_idx(int row, int col) {
  return row * 128 + (((((col) >> 3) ^ (row & 7)) & 15) << 3) + (col & 7);
}

// ---------------------------------------------------------------------------
// E1: x1[n,j] = eb1[j] + sum_k h[n,k]*ew1[j,k]   (2048 x 64)
__global__ __launch_bounds__(256) void extract1(
    const float* __restrict__ h, const float* __restrict__ ew1,
    const float* __restrict__ eb1, float* __restrict__ x1)
{
  int idx = blockIdx.x * 256 + threadIdx.x;   // 131072 total
  int n = idx >> 6, j = idx & 63;
  const float4* hr = (const float4*)(h + (size_t)n * 128);
  const float4* wr = (const float4*)(ew1 + (size_t)j * 128);
  float acc = eb1[j];
#pragma unroll
  for (int k4 = 0; k4 < 32; ++k4) {
    float4 a = hr[k4], w = wr[k4];
    acc += a.x * w.x + a.y * w.y + a.z * w.z + a.w * w.w;
  }
  x1[idx] = acc;
}

// ---------------------------------------------------------------------------
// E2: pooled = adj @ x1, deg = rowsum(adj); x2 = pooled/deg + eps1*x1
__global__ __launch_bounds__(256) void extract2(
    const float* __restrict__ adj, const float* __restrict__ x1,
    const float* __restrict__ eps1, float* __restrict__ x2)
{
  const int n0 = blockIdx.x * 16;
  const int t = threadIdx.x;
  __shared__ float adj_l[16][256];   // 16KB
  __shared__ float x1_l[256][64];    // 64KB
  __shared__ float deg_l[16];
  if (t < 16) deg_l[t] = 0.f;
  __syncthreads();
  const int j = t & 63, rg = t >> 6;
  float acc[4] = {0.f, 0.f, 0.f, 0.f};
  for (int kc = 0; kc < 2048; kc += 256) {
    for (int f4 = t; f4 < 16 * 64; f4 += 256) {
      int r = f4 >> 6, q = f4 & 63;
      *(float4*)&adj_l[r][q * 4] =
          *(const float4*)&adj[(size_t)(n0 + r) * 2048 + kc + q * 4];
    }
    for (int f4 = t; f4 < 256 * 16; f4 += 256) {
      int kk = f4 >> 4, q = f4 & 15;
      *(float4*)&x1_l[kk][q * 4] =
          *(const float4*)&x1[(size_t)(kc + kk) * 64 + q * 4];
    }
    __syncthreads();
    {
      int r = t >> 4, l16 = t & 15;
      float p = 0.f;
      for (int kk = l16; kk < 256; kk += 16) p += adj_l[r][kk];
      for (int s = 8; s; s >>= 1) p += __shfl_down(p, s, 16);
      if (l16 == 0) deg_l[r] += p;
    }
    for (int kk = 0; kk < 256; ++kk) {
      float xv = x1_l[kk][j];
#pragma unroll
      for (int rr = 0; rr < 4; ++rr) acc[rr] += adj_l[rg * 4 + rr][kk] * xv;
    }
    __syncthreads();
  }
  const float ep = eps1[0];
#pragma unroll
  for (int rr = 0; rr < 4; ++rr) {
    int r = rg * 4 + rr;
    float d = deg_l[r];
    d = (d < 1e-6f) ? 1.f : d;
    size_t off = (size_t)(n0 + r) * 64 + j;
    x2[off] = acc[rr] / d + ep * x1[off];
  }
}

// ---------------------------------------------------------------------------
// E3a: partial BN sums over 32-row stripes -> psum/pqsum[64][64]
__global__ __launch_bounds__(256) void extract3a(
    const float* __restrict__ x2, float* __restrict__ psum,
    float* __restrict__ pqsum)
{
  int g = blockIdx.x;            // 64 blocks, 32 rows each
  int t = threadIdx.x, j = t & 63, rg = t >> 6;
  __shared__ float sl[4][64], ql[4][64];
  float s = 0.f, q = 0.f;
  for (int r = g * 32 + rg; r < g * 32 + 32; r += 4) {
    float v = x2[(size_t)r * 64 + j];
    s += v; q += v * v;
  }
  sl[rg][j] = s; ql[rg][j] = q;
  __syncthreads();
  if (t < 64) {
    psum[g * 64 + t]  = sl[0][t] + sl[1][t] + sl[2][t] + sl[3][t];
    pqsum[g * 64 + t] = ql[0][t] + ql[1][t] + ql[2][t] + ql[3][t];
  }
}

// E3b: finalize scale/shift
__global__ void extract3b(
    const float* __restrict__ psum, const float* __restrict__ pqsum,
    const float* __restrict__ bnw, const float* __restrict__ bnb,
    float* __restrict__ scale, float* __restrict__ shift)
{
  int j = threadIdx.x;   // 64 threads
  float s = 0.f, q = 0.f;
  for (int g = 0; g < 64; ++g) { s += psum[g * 64 + j]; q += pqsum[g * 64 + j]; }
  float mean = s * (1.f / 2048.f);
  float var = q * (1.f / 2048.f) - mean * mean;
  float rstd = rsqrtf(var + 1e-5f);
  float sc = rstd * bnw[j];
  scale[j] = sc;
  shift[j] = bnb[j] - mean * sc;
}

// ---------------------------------------------------------------------------
// E4: xn = x2*scale+shift; feat = xn@ew2.T+eb2; fp = feat@wg+bg;
//     fplH[n,o] = (fp16)( wl_b[o] + sum_e fp[n,e]*wl_w[o,64+e] )
__global__ __launch_bounds__(256) void extract4(
    const float* __restrict__ x2, const float* __restrict__ scale,
    const float* __restrict__ shift, const float* __restrict__ ew2,
    const float* __restrict__ eb2, const float* __restrict__ wg,
    const float* __restrict__ bg, const float* __restrict__ wl_w,
    const float* __restrict__ wl_b, _Float16* __restrict__ fplH)
{
  __shared__ float xn[4][64], ft[4][64], fp[4][64];
  int t = threadIdx.x, sub = t >> 6, o = t & 63;
  int n = blockIdx.x * 4 + sub;
  xn[sub][o] = x2[(size_t)n * 64 + o] * scale[o] + shift[o];
  __syncthreads();
  {
    float acc = eb2[o];
    for (int k = 0; k < 64; ++k) acc += xn[sub][k] * ew2[o * 64 + k];
    ft[sub][o] = acc;
  }
  __syncthreads();
  {
    float acc = bg[0];
    for (int k = 0; k < 64; ++k) acc += ft[sub][k] * wg[k * 64 + o];
    fp[sub][o] = acc;
  }
  __syncthreads();
  {
    float acc = wl_b[o];
    for (int k = 0; k < 64; ++k) acc += fp[sub][k] * wl_w[o * 128 + 64 + k];
    fplH[(size_t)n * 64 + o] = (_Float16)acc;
  }
}

// ---------------------------------------------------------------------------
// Weight -> fp16 fragment arrays. k-map within a 32-step: kk = (l>>4)*8 + e
// (any bijection works as long as A staging uses the same map).
// w1f: [nt(8)][ks(2)][l(64)][e(8)]  from w1 rows 1..64 (k part)
// w2f: [nt(4)][ks(2)][l][e]          from w2 rows 1..64
// wlf: [nt(4)][ks(2)][l][e]          B[k][o] = wl_w[o*128 + k], k<64
__global__ __launch_bounds__(256) void prep_frags(
    const float* __restrict__ w1, const float* __restrict__ w2,
    const float* __restrict__ wl_w, _Float16* __restrict__ w1f,
    _Float16* __restrict__ w2f, _Float16* __restrict__ wlf)
{
  int idx = blockIdx.x * 256 + threadIdx.x;   // 16384 total
  int e = idx & 7, l = (idx >> 3) & 63;
  int kk = ((l >> 4) * 8) + e;                // 0..31 within a K-step
  if (idx < 8192) {
    int ks = (idx >> 9) & 1, nt = idx >> 10;  // nt 0..7
    int k = ks * 32 + kk;
    w1f[idx] = (_Float16)w1[(1 + k) * 128 + nt * 16 + (l & 15)];
  } else if (idx < 12288) {
    int i2 = idx - 8192;
    int ks = (i2 >> 9) & 1, nt = i2 >> 10;    // nt 0..3
    int k = ks * 32 + kk;
    w2f[i2] = (_Float16)w2[(1 + k) * 64 + nt * 16 + (l & 15)];
  } else {
    int i3 = idx - 12288;
    int ks = (i3 >> 9) & 1, nt = i3 >> 10;    // nt 0..3
    int k = ks * 32 + kk;
    wlf[i3] = (_Float16)wl_w[(nt * 16 + (l & 15)) * 128 + k];
  }
}

// ---------------------------------------------------------------------------
// One GRU step, fp16 MFMA. Block: batch b (blockIdx.y), nodes [a, a+64).
// 256 threads = 4 waves. Split semantics: own node n uses ru row (n-a)>>1 (r)
// and 32+((n-a)>>1) (u) at gate offset ((n&1)<<6)+h.
__global__ __launch_bounds__(256, 4) void gru_step(
    const float* __restrict__ hs_in, float* __restrict__ hs_out,
    const float* __restrict__ inputs, int tstep, int first,
    const float* __restrict__ w1, const float* __restrict__ b1,
    const float* __restrict__ w2, const float* __restrict__ b2,
    const _Float16* __restrict__ fplH, const _Float16* __restrict__ w1f,
    const _Float16* __restrict__ w2f, const _Float16* __restrict__ wlf)
{
  const int b = blockIdx.y;
  const int a = blockIdx.x * 64;
  const int t = threadIdx.x;
  const int l = t & 63, wv = t >> 6;
  const int halfBase = a >> 1;

  __shared__ __align__(16) _Float16 A1f[4096];   // 8KB: hs_src frags; reused as A3 (new)
  __shared__ __align__(16) _Float16 A2f[4096];   // 8KB: rh frags
  __shared__ __align__(16) _Float16 ruF[8192];   // 16KB: gates (swizzled)
  __shared__ float xts[64], xto[64];

  const float* xt  = inputs + (size_t)(b * 12 + tstep) * 2048;
  const float* hsb = hs_in + (size_t)b * 131072;

  if (t < 64) {
    xto[t] = xt[a + t];
  } else if (t < 128) {
    int m = t - 64;
    int ns = (m < 32) ? (halfBase + m) : (1024 + halfBase + m - 32);
    xts[m] = xt[ns];
  }

  // ---- stage A1 = hs_src fp16 frags (chunk i: node m=i>>3, k8=i&7)
  for (int i = t; i < 512; i += 256) {
    int m = i >> 3, k8 = i & 7;
    half8 v;
    if (first) {
#pragma unroll
      for (int e = 0; e < 8; ++e) v[e] = (_Float16)0.f;
    } else {
      int ns = (m < 32) ? (halfBase + m) : (1024 + halfBase + m - 32);
      float4 p0 = *(const float4*)&hsb[(size_t)ns * 64 + k8 * 8];
      float4 p1 = *(const float4*)&hsb[(size_t)ns * 64 + k8 * 8 + 4];
      v[0] = (_Float16)p0.x; v[1] = (_Float16)p0.y;
      v[2] = (_Float16)p0.z; v[3] = (_Float16)p0.w;
      v[4] = (_Float16)p1.x; v[5] = (_Float16)p1.y;
      v[6] = (_Float16)p1.z; v[7] = (_Float16)p1.w;
    }
    int mt = m >> 4, ks = k8 >> 2, kc = k8 & 3;
    *(half8*)&A1f[(((mt * 2 + ks) * 64) + ((m & 15) | (kc << 4))) * 8] = v;
  }
  __syncthreads();

  // ---- Phase 1: ru = sigmoid(b1 + xt_src*w1_row0 + hs_src @ w1_rows1..64)
  {
    half8 B1[2][2];
#pragma unroll
    for (int q = 0; q < 2; ++q)
#pragma unroll
      for (int ks = 0; ks < 2; ++ks)
        B1[q][ks] = *(const half8*)&w1f[((((2 * wv + q) * 2 + ks) * 64) + l) * 8];
#pragma unroll
    for (int mt = 0; mt < 4; ++mt) {
      half8 Aa = *(half8*)&A1f[(((mt * 2 + 0) * 64) + l) * 8];
      half8 Ab = *(half8*)&A1f[(((mt * 2 + 1) * 64) + l) * 8];
      int r0 = mt * 16 + (l >> 4) * 4;
#pragma unroll
      for (int q = 0; q < 2; ++q) {
        int nt = 2 * wv + q;
        int col = nt * 16 + (l & 15);
        float bcol = b1[col], w1x = w1[col];
        f32x4 acc;
        acc[0] = bcol + xts[r0 + 0] * w1x;
        acc[1] = bcol + xts[r0 + 1] * w1x;
        acc[2] = bcol + xts[r0 + 2] * w1x;
        acc[3] = bcol + xts[r0 + 3] * w1x;
        acc = mfma16(Aa, B1[q][0], acc);
        acc = mfma16(Ab, B1[q][1], acc);
#pragma unroll
        for (int qq = 0; qq < 4; ++qq) {
          float s = 1.f / (1.f + __expf(-acc[qq]));
          ruF[ru_idx(r0 + qq, col)] = (_Float16)s;
        }
      }
    }
  }
  __syncthreads();

  // ---- Phase 2a: A2 = rh frags: rh[n][k] = r[n][k]*hs_own[n][k]
  for (int i = t; i < 512; i += 256) {
    int n = i >> 3, k8 = i & 7;
    int c0 = ((n & 1) << 6) + k8 * 8;
    half8 rv = *(half8*)&ruF[ru_idx(n >> 1, c0)];
    half8 v;
    if (first) {
#pragma unroll
      for (int e = 0; e < 8; ++e) v[e] = (_Float16)0.f;
    } else {
      float4 p0 = *(const float4*)&hsb[(size_t)(a + n) * 64 + k8 * 8];
      float4 p1 = *(const float4*)&hsb[(size_t)(a + n) * 64 + k8 * 8 + 4];
      v[0] = (_Float16)((float)rv[0] * p0.x);
      v[1] = (_Float16)((float)rv[1] * p0.y);
      v[2] = (_Float16)((float)rv[2] * p0.z);
      v[3] = (_Float16)((float)rv[3] * p0.w);
      v[4] = (_Float16)((float)rv[4] * p1.x);
      v[5] = (_Float16)((float)rv[5] * p1.y);
      v[6] = (_Float16)((float)rv[6] * p1.z);
      v[7] = (_Float16)((float)rv[7] * p1.w);
    }
    int mt = n >> 4, ks = k8 >> 2, kc = k8 & 3;
    *(half8*)&A2f[(((mt * 2 + ks) * 64) + ((n & 15) | (kc << 4))) * 8] = v;
  }
  __syncthreads();

  // ---- Phase 2b: c = tanh(b2 + xt_own*w2_row0 + rh @ w2_rows1..64)
  //      fused epilogue: new = u*hs + (1-u)*c  -> A3 frags (into A1f)
  {
    int nt = wv;
    half8 B2a = *(const half8*)&w2f[(((nt * 2 + 0) * 64) + l) * 8];
    half8 B2b = *(const half8*)&w2f[(((nt * 2 + 1) * 64) + l) * 8];
    int col = nt * 16 + (l & 15);
    float b2c = b2[col], w2x = w2[col];
#pragma unroll
    for (int mt = 0; mt < 4; ++mt) {
      half8 Aa = *(half8*)&A2f[(((mt * 2 + 0) * 64) + l) * 8];
      half8 Ab = *(half8*)&A2f[(((mt * 2 + 1) * 64) + l) * 8];
      int r0 = mt * 16 + (l >> 4) * 4;
      f32x4 acc;
      acc[0] = b2c + xto[r0 + 0] * w2x;
      acc[1] = b2c + xto[r0 + 1] * w2x;
      acc[2] = b2c + xto[r0 + 2] * w2x;
      acc[3] = b2c + xto[r0 + 3] * w2x;
      acc = mfma16(Aa, B2a, acc);
      acc = mfma16(Ab, B2b, acc);
#pragma unroll
      for (int qq = 0; qq < 4; ++qq) {
        int row = r0 + qq;
        float e2 = __expf(2.f * acc[qq]);
        float cv = 1.f - 2.f / (e2 + 1.f);   // tanh
        float u = (float)ruF[ru_idx(32 + (row >> 1), ((row & 1) << 6) + col)];
        float hsv = first ? 0.f : hsb[(size_t)(a + row) * 64 + col];
        float nv = u * hsv + (1.f - u) * cv;
        // A3 fragment slot for element (n=row, k=col):
        int mt3 = row >> 4, ks3 = col >> 5;
        int l3 = (row & 15) | (((col >> 3) & 3) << 4);
        A1f[(((mt3 * 2 + ks3) * 64) + l3) * 8 + (col & 7)] = (_Float16)nv;
      }
    }
  }
  __syncthreads();

  // ---- Phase 3b: out = fplH + new @ wlT  (MFMA over A3)
  {
    int nt = wv;
    half8 B3a = *(const half8*)&wlf[(((nt * 2 + 0) * 64) + l) * 8];
    half8 B3b = *(const half8*)&wlf[(((nt * 2 + 1) * 64) + l) * 8];
    int col = nt * 16 + (l & 15);
#pragma unroll
    for (int mt = 0; mt < 4; ++mt) {
      half8 Aa = *(half8*)&A1f[(((mt * 2 + 0) * 64) + l) * 8];
      half8 Ab = *(half8*)&A1f[(((mt * 2 + 1) * 64) + l) * 8];
      int r0 = mt * 16 + (l >> 4) * 4;
      f32x4 acc;
      acc[0] = (float)fplH[(size_t)(a + r0 + 0) * 64 + col];
      acc[1] = (float)fplH[(size_t)(a + r0 + 1) * 64 + col];
      acc[2] = (float)fplH[(size_t)(a + r0 + 2) * 64 + col];
      acc[3] = (float)fplH[(size_t)(a + r0 + 3) * 64 + col];
      acc = mfma16(Aa, B3a, acc);
      acc = mfma16(Ab, B3b, acc);
#pragma unroll
      for (int qq = 0; qq < 4; ++qq) {
        hs_out[(size_t)b * 131072 + (size_t)(a + r0 + qq) * 64 + col] = acc[qq];
      }
    }
  }
}

// ---------------------------------------------------------------------------
extern "C" void kernel_launch(void* const* d_in, const int* in_sizes, int n_in,
                              void* d_out, int out_size, void* d_ws, size_t ws_size,
                              hipStream_t stream) {
  const float* h      = (const float*)d_in[0];
  const float* adj    = (const float*)d_in[1];
  const float* inputs = (const float*)d_in[2];
  const float* ew1    = (const float*)d_in[3];
  const float* eb1    = (const float*)d_in[4];
  const float* ew2    = (const float*)d_in[5];
  const float* eb2    = (const float*)d_in[6];
  const float* eps1   = (const float*)d_in[7];
  const float* bnw    = (const float*)d_in[8];
  const float* bnb    = (const float*)d_in[9];
  const float* w1     = (const float*)d_in[10];
  const float* b1     = (const float*)d_in[11];
  const float* w2     = (const float*)d_in[12];
  const float* b2     = (const float*)d_in[13];
  const float* wg     = (const float*)d_in[14];
  const float* bg     = (const float*)d_in[15];
  const float* wl_w   = (const float*)d_in[16];
  const float* wl_b   = (const float*)d_in[17];

  float* out = (float*)d_out;
  float* ws  = (float*)d_ws;

  // ws layout (floats):
  //  [0, 8388608)            hs ping buffer
  //    aliased pre-GRU: x1 @0 (131072), x2 @131072 (131072),
  //                     psum @262144 (4096), pqsum @266240 (4096),
  //                     scale @270336 (64), shift @270400 (64)
  //  [8388608, +65536)       fplH (fp16, 131072 halfs)
  //  then w1f (8192 halfs), w2f (4096 halfs), wlf (4096 halfs)
  float* hs_ws = ws;
  float* x1    = ws;
  float* x2    = ws + 131072;
  float* psum  = ws + 262144;
  float* pqsum = ws + 266240;
  float* scale = ws + 270336;
  float* shift = ws + 270400;
  _Float16* fplH = (_Float16*)(ws + 8388608);
  _Float16* w1f  = (_Float16*)(ws + 8388608 + 65536);
  _Float16* w2f  = w1f + 8192;
  _Float16* wlf  = w2f + 4096;

  extract1<<<512, 256, 0, stream>>>(h, ew1, eb1, x1);
  extract2<<<128, 256, 0, stream>>>(adj, x1, eps1, x2);
  extract3a<<<64, 256, 0, stream>>>(x2, psum, pqsum);
  extract3b<<<1, 64, 0, stream>>>(psum, pqsum, bnw, bnb, scale, shift);
  extract4<<<512, 256, 0, stream>>>(x2, scale, shift, ew2, eb2, wg, bg,
                                    wl_w, wl_b, fplH);
  prep_frags<<<64, 256, 0, stream>>>(w1, w2, wl_w, w1f, w2f, wlf);

  dim3 grid(32, 64);
  for (int t = 0; t < 12; ++t) {
    float* obuf = (t & 1) ? out : hs_ws;
    const float* ibuf = (t & 1) ? hs_ws : out;   // t=0 ignores ibuf (first=1)
    gru_step<<<grid, 256, 0, stream>>>(ibuf, obuf, inputs, t, (t == 0) ? 1 : 0,
                                       w1, b1, w2, b2, fplH, w1f, w2f, wlf);
  }
}

// Round 4
// 397.648 us; speedup vs baseline: 4.8693x; 1.1604x over previous
//
#include <hip/hip_runtime.h>
#include <cstdint>

// Problem dims: N=2048, IN_DIM=128, HID=64, ENC=64, B=64, SEQ=12

typedef _Float16 half8 __attribute__((ext_vector_type(8)));
typedef float f32x4 __attribute__((ext_vector_type(4)));

static __device__ inline f32x4 mfma16(half8 a, half8 b, f32x4 c) {
  return __builtin_amdgcn_mfma_f32_16x16x32_f16(a, b, c, 0, 0, 0);
}

// ru LDS addressing: fp16 [64 rows][128 cols], XOR-swizzled at 8-half granularity.
static __device__ inline int ru_idx(int row, int col) {
  return row * 128 + (((((col) >> 3) ^ (row & 7)) & 15) << 3) + (col & 7);
}

// ---------------------------------------------------------------------------
// E1: x1[n,j] = eb1[j] + sum_k h[n,k]*ew1[j,k]   (2048 x 64)
__global__ __launch_bounds__(256) void extract1(
    const float* __restrict__ h, const float* __restrict__ ew1,
    const float* __restrict__ eb1, float* __restrict__ x1)
{
  int idx = blockIdx.x * 256 + threadIdx.x;   // 131072 total
  int n = idx >> 6, j = idx & 63;
  const float4* hr = (const float4*)(h + (size_t)n * 128);
  const float4* wr = (const float4*)(ew1 + (size_t)j * 128);
  float acc = eb1[j];
#pragma unroll
  for (int k4 = 0; k4 < 32; ++k4) {
    float4 a = hr[k4], w = wr[k4];
    acc += a.x * w.x + a.y * w.y + a.z * w.z + a.w * w.w;
  }
  x1[idx] = acc;
}

// ---------------------------------------------------------------------------
// x1 -> fp16 B-fragment array: x1f[ks(64)][nt(4)][l(64)][e(8)]
// B[k][col], col = nt*16 + (l&15), k = ks*32 + (l>>4)*8 + e
__global__ __launch_bounds__(256) void prep_x1f(
    const float* __restrict__ x1, _Float16* __restrict__ x1f)
{
  int idx = blockIdx.x * 256 + threadIdx.x;   // 131072
  int e = idx & 7, l = (idx >> 3) & 63, nt = (idx >> 9) & 3, ks = idx >> 11;
  int k = ks * 32 + ((l >> 4) * 8) + e;
  int col = nt * 16 + (l & 15);
  x1f[idx] = (_Float16)x1[k * 64 + col];
}

// ---------------------------------------------------------------------------
// E2 (MFMA): pooled = adj @ x1 (fp16 frags), deg = rowsum(adj) in fp32;
//            x2 = pooled/deg + eps1*x1
// 256 blocks x 8 rows. 256 threads = 4 waves; wave w = col-tile nt=w.
__global__ __launch_bounds__(256) void extract2_mfma(
    const float* __restrict__ adj, const float* __restrict__ x1,
    const _Float16* __restrict__ x1f, const float* __restrict__ eps1,
    float* __restrict__ x2)
{
  const int n0 = blockIdx.x * 8;
  const int t = threadIdx.x;
  const int l = t & 63, wv = t >> 6;
  __shared__ __align__(16) _Float16 Abuf[4096];   // 8 K-steps x 64 lanes x 8 = 8KB
  __shared__ float deg_l[8];

  // zero all A slots once (rows 8..15 of the M-tile stay zero forever)
  for (int i = t; i < 4096; i += 256) Abuf[i] = (_Float16)0.f;

  const int row = t >> 5;           // 0..7
  const int kcol = (t & 31) * 8;    // 0..248 within a 256-k chunk
  const int s_my = (t & 31) >> 2;   // K-step within chunk (0..7)
  const int c_my = t & 3;           // 8-group within step

  float degp = 0.f;
  f32x4 acc = {0.f, 0.f, 0.f, 0.f};

  for (int kc = 0; kc < 8; ++kc) {
    __syncthreads();
    {
      const float* src = &adj[(size_t)(n0 + row) * 2048 + kc * 256 + kcol];
      float4 p0 = *(const float4*)src;
      float4 p1 = *(const float4*)(src + 4);
      degp += p0.x + p0.y + p0.z + p0.w + p1.x + p1.y + p1.z + p1.w;
      half8 v;
      v[0] = (_Float16)p0.x; v[1] = (_Float16)p0.y;
      v[2] = (_Float16)p0.z; v[3] = (_Float16)p0.w;
      v[4] = (_Float16)p1.x; v[5] = (_Float16)p1.y;
      v[6] = (_Float16)p1.z; v[7] = (_Float16)p1.w;
      *(half8*)&Abuf[(size_t)(s_my * 64 + (row | (c_my << 4))) * 8] = v;
    }
    __syncthreads();
#pragma unroll
    for (int s = 0; s < 8; ++s) {
      half8 A = *(half8*)&Abuf[(s * 64 + l) * 8];
      half8 B = *(const half8*)&x1f[(size_t)(((kc * 8 + s) * 4 + wv) * 64 + l) * 8];
      acc = mfma16(A, B, acc);
    }
  }

  // deg: reduce each row's 32 staging threads
  for (int sh = 16; sh >= 1; sh >>= 1) degp += __shfl_down(degp, sh, 32);
  if ((t & 31) == 0) deg_l[row] = degp;
  __syncthreads();

  const float ep = eps1[0];
  int colc = wv * 16 + (l & 15);
  int r0 = (l >> 4) * 4;
  if (r0 < 8) {
#pragma unroll
    for (int q = 0; q < 4; ++q) {
      int r = r0 + q;
      float d = deg_l[r];
      d = (d < 1e-6f) ? 1.f : d;
      size_t off = (size_t)(n0 + r) * 64 + colc;
      x2[off] = acc[q] / d + ep * x1[off];
    }
  }
}

// ---------------------------------------------------------------------------
// E3a: partial BN sums over 32-row stripes -> psum/pqsum[64][64]
__global__ __launch_bounds__(256) void extract3a(
    const float* __restrict__ x2, float* __restrict__ psum,
    float* __restrict__ pqsum)
{
  int g = blockIdx.x;
  int t = threadIdx.x, j = t & 63, rg = t >> 6;
  __shared__ float sl[4][64], ql[4][64];
  float s = 0.f, q = 0.f;
  for (int r = g * 32 + rg; r < g * 32 + 32; r += 4) {
    float v = x2[(size_t)r * 64 + j];
    s += v; q += v * v;
  }
  sl[rg][j] = s; ql[rg][j] = q;
  __syncthreads();
  if (t < 64) {
    psum[g * 64 + t]  = sl[0][t] + sl[1][t] + sl[2][t] + sl[3][t];
    pqsum[g * 64 + t] = ql[0][t] + ql[1][t] + ql[2][t] + ql[3][t];
  }
}

__global__ void extract3b(
    const float* __restrict__ psum, const float* __restrict__ pqsum,
    const float* __restrict__ bnw, const float* __restrict__ bnb,
    float* __restrict__ scale, float* __restrict__ shift)
{
  int j = threadIdx.x;   // 64 threads
  float s = 0.f, q = 0.f;
  for (int g = 0; g < 64; ++g) { s += psum[g * 64 + j]; q += pqsum[g * 64 + j]; }
  float mean = s * (1.f / 2048.f);
  float var = q * (1.f / 2048.f) - mean * mean;
  float rstd = rsqrtf(var + 1e-5f);
  float sc = rstd * bnw[j];
  scale[j] = sc;
  shift[j] = bnb[j] - mean * sc;
}

// ---------------------------------------------------------------------------
// E4: xn = x2*scale+shift; feat = xn@ew2.T+eb2; fp = feat@wg+bg;
//     fplH[n,o] = (fp16)( wl_b[o] + sum_e fp[n,e]*wl_w[o,64+e] )
__global__ __launch_bounds__(256) void extract4(
    const float* __restrict__ x2, const float* __restrict__ scale,
    const float* __restrict__ shift, const float* __restrict__ ew2,
    const float* __restrict__ eb2, const float* __restrict__ wg,
    const float* __restrict__ bg, const float* __restrict__ wl_w,
    const float* __restrict__ wl_b, _Float16* __restrict__ fplH)
{
  __shared__ float xn[4][64], ft[4][64], fp[4][64];
  int t = threadIdx.x, sub = t >> 6, o = t & 63;
  int n = blockIdx.x * 4 + sub;
  xn[sub][o] = x2[(size_t)n * 64 + o] * scale[o] + shift[o];
  __syncthreads();
  {
    float acc = eb2[o];
    for (int k = 0; k < 64; ++k) acc += xn[sub][k] * ew2[o * 64 + k];
    ft[sub][o] = acc;
  }
  __syncthreads();
  {
    float acc = bg[0];
    for (int k = 0; k < 64; ++k) acc += ft[sub][k] * wg[k * 64 + o];
    fp[sub][o] = acc;
  }
  __syncthreads();
  {
    float acc = wl_b[o];
    for (int k = 0; k < 64; ++k) acc += fp[sub][k] * wl_w[o * 128 + 64 + k];
    fplH[(size_t)n * 64 + o] = (_Float16)acc;
  }
}

// ---------------------------------------------------------------------------
// Weight -> fp16 fragment arrays (k-map: kk = (l>>4)*8 + e).
__global__ __launch_bounds__(256) void prep_frags(
    const float* __restrict__ w1, const float* __restrict__ w2,
    const float* __restrict__ wl_w, _Float16* __restrict__ w1f,
    _Float16* __restrict__ w2f, _Float16* __restrict__ wlf)
{
  int idx = blockIdx.x * 256 + threadIdx.x;   // 16384 total
  int e = idx & 7, l = (idx >> 3) & 63;
  int kk = ((l >> 4) * 8) + e;
  if (idx < 8192) {
    int ks = (idx >> 9) & 1, nt = idx >> 10;  // nt 0..7
    int k = ks * 32 + kk;
    w1f[idx] = (_Float16)w1[(1 + k) * 128 + nt * 16 + (l & 15)];
  } else if (idx < 12288) {
    int i2 = idx - 8192;
    int ks = (i2 >> 9) & 1, nt = i2 >> 10;    // nt 0..3
    int k = ks * 32 + kk;
    w2f[i2] = (_Float16)w2[(1 + k) * 64 + nt * 16 + (l & 15)];
  } else {
    int i3 = idx - 12288;
    int ks = (i3 >> 9) & 1, nt = i3 >> 10;    // nt 0..3
    int k = ks * 32 + kk;
    wlf[i3] = (_Float16)wl_w[(nt * 16 + (l & 15)) * 128 + k];
  }
}

// ---------------------------------------------------------------------------
// One GRU step, fp16 MFMA, fp16 hs state. Block: batch b, nodes [a, a+64).
__global__ __launch_bounds__(256, 4) void gru_step(
    const _Float16* __restrict__ hs_in, void* __restrict__ hs_out_v,
    int outF32, const float* __restrict__ inputs, int tstep, int first,
    const float* __restrict__ w1, const float* __restrict__ b1,
    const float* __restrict__ w2, const float* __restrict__ b2,
    const _Float16* __restrict__ fplH, const _Float16* __restrict__ w1f,
    const _Float16* __restrict__ w2f, const _Float16* __restrict__ wlf)
{
  const int b = blockIdx.y;
  const int a = blockIdx.x * 64;
  const int t = threadIdx.x;
  const int l = t & 63, wv = t >> 6;
  const int halfBase = a >> 1;

  __shared__ __align__(16) _Float16 A1f[4096];   // 8KB: hs_src frags; reused as A3
  __shared__ __align__(16) _Float16 A2f[4096];   // 8KB: rh frags
  __shared__ __align__(16) _Float16 ruF[8192];   // 16KB: gates (swizzled)
  __shared__ float xts[64], xto[64];

  const float* xt  = inputs + (size_t)(b * 12 + tstep) * 2048;
  const _Float16* hsb = hs_in + (size_t)b * 131072;

  if (t < 64) {
    xto[t] = xt[a + t];
  } else if (t < 128) {
    int m = t - 64;
    int ns = (m < 32) ? (halfBase + m) : (1024 + halfBase + m - 32);
    xts[m] = xt[ns];
  }

  // ---- stage A1 = hs_src fp16 frags
  for (int i = t; i < 512; i += 256) {
    int m = i >> 3, k8 = i & 7;
    half8 v;
    if (first) {
#pragma unroll
      for (int e = 0; e < 8; ++e) v[e] = (_Float16)0.f;
    } else {
      int ns = (m < 32) ? (halfBase + m) : (1024 + halfBase + m - 32);
      v = *(const half8*)&hsb[(size_t)ns * 64 + k8 * 8];
    }
    int mt = m >> 4, ks = k8 >> 2, kc = k8 & 3;
    *(half8*)&A1f[(((mt * 2 + ks) * 64) + ((m & 15) | (kc << 4))) * 8] = v;
  }
  __syncthreads();

  // ---- Phase 1: ru = sigmoid(b1 + xt_src*w1_row0 + hs_src @ w1_rows1..64)
  {
    half8 B1[2][2];
#pragma unroll
    for (int q = 0; q < 2; ++q)
#pragma unroll
      for (int ks = 0; ks < 2; ++ks)
        B1[q][ks] = *(const half8*)&w1f[((((2 * wv + q) * 2 + ks) * 64) + l) * 8];
#pragma unroll
    for (int mt = 0; mt < 4; ++mt) {
      half8 Aa = *(half8*)&A1f[(((mt * 2 + 0) * 64) + l) * 8];
      half8 Ab = *(half8*)&A1f[(((mt * 2 + 1) * 64) + l) * 8];
      int r0 = mt * 16 + (l >> 4) * 4;
#pragma unroll
      for (int q = 0; q < 2; ++q) {
        int nt = 2 * wv + q;
        int col = nt * 16 + (l & 15);
        float bcol = b1[col], w1x = w1[col];
        f32x4 acc;
        acc[0] = bcol + xts[r0 + 0] * w1x;
        acc[1] = bcol + xts[r0 + 1] * w1x;
        acc[2] = bcol + xts[r0 + 2] * w1x;
        acc[3] = bcol + xts[r0 + 3] * w1x;
        acc = mfma16(Aa, B1[q][0], acc);
        acc = mfma16(Ab, B1[q][1], acc);
#pragma unroll
        for (int qq = 0; qq < 4; ++qq) {
          float s = 1.f / (1.f + __expf(-acc[qq]));
          ruF[ru_idx(r0 + qq, col)] = (_Float16)s;
        }
      }
    }
  }
  __syncthreads();

  // ---- Phase 2a: A2 = rh frags: rh[n][k] = r[n][k]*hs_own[n][k]
  for (int i = t; i < 512; i += 256) {
    int n = i >> 3, k8 = i & 7;
    int c0 = ((n & 1) << 6) + k8 * 8;
    half8 rv = *(half8*)&ruF[ru_idx(n >> 1, c0)];
    half8 v;
    if (first) {
#pragma unroll
      for (int e = 0; e < 8; ++e) v[e] = (_Float16)0.f;
    } else {
      half8 hv = *(const half8*)&hsb[(size_t)(a + n) * 64 + k8 * 8];
#pragma unroll
      for (int e = 0; e < 8; ++e)
        v[e] = (_Float16)((float)rv[e] * (float)hv[e]);
    }
    int mt = n >> 4, ks = k8 >> 2, kc = k8 & 3;
    *(half8*)&A2f[(((mt * 2 + ks) * 64) + ((n & 15) | (kc << 4))) * 8] = v;
  }
  __syncthreads();

  // ---- Phase 2b: c = tanh(...); fused: new = u*hs + (1-u)*c -> A3 frags
  {
    int nt = wv;
    half8 B2a = *(const half8*)&w2f[(((nt * 2 + 0) * 64) + l) * 8];
    half8 B2b = *(const half8*)&w2f[(((nt * 2 + 1) * 64) + l) * 8];
    int col = nt * 16 + (l & 15);
    float b2c = b2[col], w2x = w2[col];
#pragma unroll
    for (int mt = 0; mt < 4; ++mt) {
      half8 Aa = *(half8*)&A2f[(((mt * 2 + 0) * 64) + l) * 8];
      half8 Ab = *(half8*)&A2f[(((mt * 2 + 1) * 64) + l) * 8];
      int r0 = mt * 16 + (l >> 4) * 4;
      f32x4 acc;
      acc[0] = b2c + xto[r0 + 0] * w2x;
      acc[1] = b2c + xto[r0 + 1] * w2x;
      acc[2] = b2c + xto[r0 + 2] * w2x;
      acc[3] = b2c + xto[r0 + 3] * w2x;
      acc = mfma16(Aa, B2a, acc);
      acc = mfma16(Ab, B2b, acc);
#pragma unroll
      for (int qq = 0; qq < 4; ++qq) {
        int row = r0 + qq;
        float e2 = __expf(2.f * acc[qq]);
        float cv = 1.f - 2.f / (e2 + 1.f);   // tanh
        float u = (float)ruF[ru_idx(32 + (row >> 1), ((row & 1) << 6) + col)];
        float hsv = first ? 0.f : (float)hsb[(size_t)(a + row) * 64 + col];
        float nv = u * hsv + (1.f - u) * cv;
        int mt3 = row >> 4, ks3 = col >> 5;
        int l3 = (row & 15) | (((col >> 3) & 3) << 4);
        A1f[(((mt3 * 2 + ks3) * 64) + l3) * 8 + (col & 7)] = (_Float16)nv;
      }
    }
  }
  __syncthreads();

  // ---- Phase 3b: out = fplH + new @ wlT
  {
    int nt = wv;
    half8 B3a = *(const half8*)&wlf[(((nt * 2 + 0) * 64) + l) * 8];
    half8 B3b = *(const half8*)&wlf[(((nt * 2 + 1) * 64) + l) * 8];
    int col = nt * 16 + (l & 15);
#pragma unroll
    for (int mt = 0; mt < 4; ++mt) {
      half8 Aa = *(half8*)&A1f[(((mt * 2 + 0) * 64) + l) * 8];
      half8 Ab = *(half8*)&A1f[(((mt * 2 + 1) * 64) + l) * 8];
      int r0 = mt * 16 + (l >> 4) * 4;
      f32x4 acc;
      acc[0] = (float)fplH[(size_t)(a + r0 + 0) * 64 + col];
      acc[1] = (float)fplH[(size_t)(a + r0 + 1) * 64 + col];
      acc[2] = (float)fplH[(size_t)(a + r0 + 2) * 64 + col];
      acc[3] = (float)fplH[(size_t)(a + r0 + 3) * 64 + col];
      acc = mfma16(Aa, B3a, acc);
      acc = mfma16(Ab, B3b, acc);
      if (outF32) {
        float* outp = (float*)hs_out_v;
#pragma unroll
        for (int qq = 0; qq < 4; ++qq)
          outp[(size_t)b * 131072 + (size_t)(a + r0 + qq) * 64 + col] = acc[qq];
      } else {
        _Float16* outp = (_Float16*)hs_out_v;
#pragma unroll
        for (int qq = 0; qq < 4; ++qq)
          outp[(size_t)b * 131072 + (size_t)(a + r0 + qq) * 64 + col] =
              (_Float16)acc[qq];
      }
    }
  }
}

// ---------------------------------------------------------------------------
extern "C" void kernel_launch(void* const* d_in, const int* in_sizes, int n_in,
                              void* d_out, int out_size, void* d_ws, size_t ws_size,
                              hipStream_t stream) {
  const float* h      = (const float*)d_in[0];
  const float* adj    = (const float*)d_in[1];
  const float* inputs = (const float*)d_in[2];
  const float* ew1    = (const float*)d_in[3];
  const float* eb1    = (const float*)d_in[4];
  const float* ew2    = (const float*)d_in[5];
  const float* eb2    = (const float*)d_in[6];
  const float* eps1   = (const float*)d_in[7];
  const float* bnw    = (const float*)d_in[8];
  const float* bnb    = (const float*)d_in[9];
  const float* w1     = (const float*)d_in[10];
  const float* b1     = (const float*)d_in[11];
  const float* w2     = (const float*)d_in[12];
  const float* b2     = (const float*)d_in[13];
  const float* wg     = (const float*)d_in[14];
  const float* bg     = (const float*)d_in[15];
  const float* wl_w   = (const float*)d_in[16];
  const float* wl_b   = (const float*)d_in[17];

  char* ws = (char*)d_ws;

  // ws layout (bytes):
  //  [0, 16777216)           h0 (fp16 hs ping, 8388608 halfs)
  //  [16777216, 33554432)    h1 (fp16 hs pong)
  //    aliased pre-GRU inside h1: x1 (131072 f32), x2 (131072 f32),
  //      x1f (131072 f16), psum (4096 f32), pqsum (4096 f32),
  //      scale (64 f32), shift (64 f32)
  //  [33554432, +262144)     fplH (131072 halfs)
  //  then w1f (8192 halfs), w2f (4096), wlf (4096)
  _Float16* h0H = (_Float16*)ws;
  _Float16* h1H = (_Float16*)(ws + 16777216);
  float* x1    = (float*)h1H;
  float* x2    = x1 + 131072;
  _Float16* x1f = (_Float16*)(x2 + 131072);
  float* psum  = (float*)(x1f + 131072);
  float* pqsum = psum + 4096;
  float* scale = pqsum + 4096;
  float* shift = scale + 64;
  _Float16* fplH = (_Float16*)(ws + 33554432);
  _Float16* w1f  = fplH + 131072;
  _Float16* w2f  = w1f + 8192;
  _Float16* wlf  = w2f + 4096;

  extract1<<<512, 256, 0, stream>>>(h, ew1, eb1, x1);
  prep_x1f<<<512, 256, 0, stream>>>(x1, x1f);
  extract2_mfma<<<256, 256, 0, stream>>>(adj, x1, x1f, eps1, x2);
  extract3a<<<64, 256, 0, stream>>>(x2, psum, pqsum);
  extract3b<<<1, 64, 0, stream>>>(psum, pqsum, bnw, bnb, scale, shift);
  extract4<<<512, 256, 0, stream>>>(x2, scale, shift, ew2, eb2, wg, bg,
                                    wl_w, wl_b, fplH);
  prep_frags<<<64, 256, 0, stream>>>(w1, w2, wl_w, w1f, w2f, wlf);

  dim3 grid(32, 64);
  for (int t = 0; t < 12; ++t) {
    // t=0 -> h0; odd t -> h1; even t -> h0; t=11 -> d_out (fp32)
    const _Float16* ibuf = (t & 1) ? h0H : h1H;   // t=0 ignores (first=1)
    void* obuf; int of32 = 0;
    if (t == 11) { obuf = d_out; of32 = 1; }
    else obuf = (t & 1) ? (void*)h1H : (void*)h0H;
    gru_step<<<grid, 256, 0, stream>>>(ibuf, obuf, of32, inputs, t,
                                       (t == 0) ? 1 : 0,
                                       w1, b1, w2, b2, fplH, w1f, w2f, wlf);
  }
}

// Round 5
// 313.114 us; speedup vs baseline: 6.1839x; 1.2700x over previous
//
#include <hip/hip_runtime.h>
#include <cstdint>

// Problem dims: N=2048, IN_DIM=128, HID=64, ENC=64, B=64, SEQ=12

typedef _Float16 half8 __attribute__((ext_vector_type(8)));
typedef _Float16 half4 __attribute__((ext_vector_type(4)));
typedef float f32x4 __attribute__((ext_vector_type(4)));

static __device__ inline f32x4 mfma16(half8 a, half8 b, f32x4 c) {
  return __builtin_amdgcn_mfma_f32_16x16x32_f16(a, b, c, 0, 0, 0);
}

static __device__ inline float fast_sigmoid(float x) {
  return __builtin_amdgcn_rcpf(1.f + __expf(-x));
}
static __device__ inline float fast_tanh(float x) {
  return 1.f - 2.f * __builtin_amdgcn_rcpf(__expf(2.f * x) + 1.f);
}

// ru LDS addressing: fp16 [64 rows][128 cols], XOR-swizzled at 8-half granularity.
static __device__ inline int ru_idx(int row, int col) {
  return row * 128 + (((((col) >> 3) ^ (row & 7)) & 15) << 3) + (col & 7);
}

// A-fragment slot (element n,k) -> half index in a 4096-half fragment buffer
static __device__ inline int afrag_idx(int n, int k) {
  return ((((n >> 4) * 2 + (k >> 5)) * 64) + ((n & 15) | (((k >> 3) & 3) << 4))) * 8
         + (k & 7);
}

// ---------------------------------------------------------------------------
// E1 fused: x1[n,j] = eb1[j] + sum_k h[n,k]*ew1[j,k]; also x1f frag (fp16)
__global__ __launch_bounds__(256) void extract1(
    const float* __restrict__ h, const float* __restrict__ ew1,
    const float* __restrict__ eb1, float* __restrict__ x1,
    _Float16* __restrict__ x1f)
{
  int idx = blockIdx.x * 256 + threadIdx.x;   // 131072 total
  int n = idx >> 6, j = idx & 63;
  const float4* hr = (const float4*)(h + (size_t)n * 128);
  const float4* wr = (const float4*)(ew1 + (size_t)j * 128);
  float acc = eb1[j];
#pragma unroll
  for (int k4 = 0; k4 < 32; ++k4) {
    float4 a = hr[k4], w = wr[k4];
    acc += a.x * w.x + a.y * w.y + a.z * w.z + a.w * w.w;
  }
  x1[idx] = acc;
  // B-frag slot for (k=n, col=j): ks=n>>5, nt=j>>4, l=(j&15)|(((n>>3)&3)<<4), e=n&7
  int ks = n >> 5, nt = j >> 4;
  int l = (j & 15) | (((n >> 3) & 3) << 4);
  x1f[(((ks * 4 + nt) * 64) + l) * 8 + (n & 7)] = (_Float16)acc;
}

// ---------------------------------------------------------------------------
// E2 (MFMA): pooled = adj @ x1 (fp16 frags), deg = rowsum(adj) fp32;
//            x2 = pooled/deg + eps1*x1
__global__ __launch_bounds__(256) void extract2_mfma(
    const float* __restrict__ adj, const float* __restrict__ x1,
    const _Float16* __restrict__ x1f, const float* __restrict__ eps1,
    float* __restrict__ x2)
{
  const int n0 = blockIdx.x * 8;
  const int t = threadIdx.x;
  const int l = t & 63, wv = t >> 6;
  __shared__ __align__(16) _Float16 Abuf[4096];
  __shared__ float deg_l[8];

  for (int i = t; i < 4096; i += 256) Abuf[i] = (_Float16)0.f;

  const int row = t >> 5;
  const int kcol = (t & 31) * 8;
  const int s_my = (t & 31) >> 2;
  const int c_my = t & 3;

  float degp = 0.f;
  f32x4 acc = {0.f, 0.f, 0.f, 0.f};

  for (int kc = 0; kc < 8; ++kc) {
    __syncthreads();
    {
      const float* src = &adj[(size_t)(n0 + row) * 2048 + kc * 256 + kcol];
      float4 p0 = *(const float4*)src;
      float4 p1 = *(const float4*)(src + 4);
      degp += p0.x + p0.y + p0.z + p0.w + p1.x + p1.y + p1.z + p1.w;
      half8 v;
      v[0] = (_Float16)p0.x; v[1] = (_Float16)p0.y;
      v[2] = (_Float16)p0.z; v[3] = (_Float16)p0.w;
      v[4] = (_Float16)p1.x; v[5] = (_Float16)p1.y;
      v[6] = (_Float16)p1.z; v[7] = (_Float16)p1.w;
      *(half8*)&Abuf[(size_t)(s_my * 64 + (row | (c_my << 4))) * 8] = v;
    }
    __syncthreads();
#pragma unroll
    for (int s = 0; s < 8; ++s) {
      half8 A = *(half8*)&Abuf[(s * 64 + l) * 8];
      half8 B = *(const half8*)&x1f[(size_t)(((kc * 8 + s) * 4 + wv) * 64 + l) * 8];
      acc = mfma16(A, B, acc);
    }
  }

  for (int sh = 16; sh >= 1; sh >>= 1) degp += __shfl_down(degp, sh, 32);
  if ((t & 31) == 0) deg_l[row] = degp;
  __syncthreads();

  const float ep = eps1[0];
  int colc = wv * 16 + (l & 15);
  int r0 = (l >> 4) * 4;
  if (r0 < 8) {
#pragma unroll
    for (int q = 0; q < 4; ++q) {
      int r = r0 + q;
      float d = deg_l[r];
      d = (d < 1e-6f) ? 1.f : d;
      size_t off = (size_t)(n0 + r) * 64 + colc;
      x2[off] = acc[q] / d + ep * x1[off];
    }
  }
}

// ---------------------------------------------------------------------------
// E3a: partial BN sums over 32-row stripes -> psum/pqsum[64][64]
__global__ __launch_bounds__(256) void extract3a(
    const float* __restrict__ x2, float* __restrict__ psum,
    float* __restrict__ pqsum)
{
  int g = blockIdx.x;
  int t = threadIdx.x, j = t & 63, rg = t >> 6;
  __shared__ float sl[4][64], ql[4][64];
  float s = 0.f, q = 0.f;
  for (int r = g * 32 + rg; r < g * 32 + 32; r += 4) {
    float v = x2[(size_t)r * 64 + j];
    s += v; q += v * v;
  }
  sl[rg][j] = s; ql[rg][j] = q;
  __syncthreads();
  if (t < 64) {
    psum[g * 64 + t]  = sl[0][t] + sl[1][t] + sl[2][t] + sl[3][t];
    pqsum[g * 64 + t] = ql[0][t] + ql[1][t] + ql[2][t] + ql[3][t];
  }
}

__global__ void extract3b(
    const float* __restrict__ psum, const float* __restrict__ pqsum,
    const float* __restrict__ bnw, const float* __restrict__ bnb,
    float* __restrict__ scale, float* __restrict__ shift)
{
  int j = threadIdx.x;   // 64 threads
  float s = 0.f, q = 0.f;
  for (int g = 0; g < 64; ++g) { s += psum[g * 64 + j]; q += pqsum[g * 64 + j]; }
  float mean = s * (1.f / 2048.f);
  float var = q * (1.f / 2048.f) - mean * mean;
  float rstd = rsqrtf(var + 1e-5f);
  float sc = rstd * bnw[j];
  scale[j] = sc;
  shift[j] = bnb[j] - mean * sc;
}

// ---------------------------------------------------------------------------
// E4: xn = x2*scale+shift; feat = xn@ew2.T+eb2; fp = feat@wg+bg;
//     fplC (C-fragment layout, fp16):
//     fplC[((tile*4+wv)*256 + mt*64 + l)*4 + qq] for element
//     (n = tile*64 + mt*16 + (l>>4)*4 + qq, o = wv*16 + (l&15))
__global__ __launch_bounds__(256) void extract4(
    const float* __restrict__ x2, const float* __restrict__ scale,
    const float* __restrict__ shift, const float* __restrict__ ew2,
    const float* __restrict__ eb2, const float* __restrict__ wg,
    const float* __restrict__ bg, const float* __restrict__ wl_w,
    const float* __restrict__ wl_b, _Float16* __restrict__ fplC)
{
  __shared__ float xn[4][64], ft[4][64], fp[4][64];
  int t = threadIdx.x, sub = t >> 6, o = t & 63;
  int n = blockIdx.x * 4 + sub;
  xn[sub][o] = x2[(size_t)n * 64 + o] * scale[o] + shift[o];
  __syncthreads();
  {
    float acc = eb2[o];
    for (int k = 0; k < 64; ++k) acc += xn[sub][k] * ew2[o * 64 + k];
    ft[sub][o] = acc;
  }
  __syncthreads();
  {
    float acc = bg[0];
    for (int k = 0; k < 64; ++k) acc += ft[sub][k] * wg[k * 64 + o];
    fp[sub][o] = acc;
  }
  __syncthreads();
  {
    float acc = wl_b[o];
    for (int k = 0; k < 64; ++k) acc += fp[sub][k] * wl_w[o * 128 + 64 + k];
    int tile = n >> 6, r = n & 63;
    int mt = r >> 4, qq = r & 3;
    int l = (o & 15) | (((r >> 2) & 3) << 4);
    fplC[(((tile * 4 + (o >> 4)) * 256) + mt * 64 + l) * 4 + qq] = (_Float16)acc;
  }
}

// ---------------------------------------------------------------------------
// Weight -> fp16 fragment arrays (k-map: kk = (l>>4)*8 + e).
__global__ __launch_bounds__(256) void prep_frags(
    const float* __restrict__ w1, const float* __restrict__ w2,
    const float* __restrict__ wl_w, _Float16* __restrict__ w1f,
    _Float16* __restrict__ w2f, _Float16* __restrict__ wlf)
{
  int idx = blockIdx.x * 256 + threadIdx.x;   // 16384 total
  int e = idx & 7, l = (idx >> 3) & 63;
  int kk = ((l >> 4) * 8) + e;
  if (idx < 8192) {
    int ks = (idx >> 9) & 1, nt = idx >> 10;  // nt 0..7
    int k = ks * 32 + kk;
    w1f[idx] = (_Float16)w1[(1 + k) * 128 + nt * 16 + (l & 15)];
  } else if (idx < 12288) {
    int i2 = idx - 8192;
    int ks = (i2 >> 9) & 1, nt = i2 >> 10;    // nt 0..3
    int k = ks * 32 + kk;
    w2f[i2] = (_Float16)w2[(1 + k) * 64 + nt * 16 + (l & 15)];
  } else {
    int i3 = idx - 12288;
    int ks = (i3 >> 9) & 1, nt = i3 >> 10;    // nt 0..3
    int k = ks * 32 + kk;
    wlf[i3] = (_Float16)wl_w[(nt * 16 + (l & 15)) * 128 + k];
  }
}

// ---------------------------------------------------------------------------
// One GRU step, fp16 MFMA, fp16 hs state. Block: batch b, nodes [a, a+64).
__global__ __launch_bounds__(256, 4) void gru_step(
    const _Float16* __restrict__ hs_in, void* __restrict__ hs_out_v,
    int outF32, const float* __restrict__ inputs, int tstep, int first,
    const float* __restrict__ w1, const float* __restrict__ b1,
    const float* __restrict__ w2, const float* __restrict__ b2,
    const _Float16* __restrict__ fplC, const _Float16* __restrict__ w1f,
    const _Float16* __restrict__ w2f, const _Float16* __restrict__ wlf)
{
  const int b = blockIdx.y;
  const int a = blockIdx.x * 64;
  const int t = threadIdx.x;
  const int l = t & 63, wv = t >> 6;
  const int halfBase = a >> 1;

  __shared__ __align__(16) _Float16 A1f[4096];   // hs_src frags -> u*hs -> new
  __shared__ __align__(16) _Float16 A2f[4096];   // rh frags
  __shared__ __align__(16) _Float16 ruF[8192];   // gates (swizzled)
  __shared__ float xts[64], xto[64];

  const float* xt  = inputs + (size_t)(b * 12 + tstep) * 2048;
  const _Float16* hsb = hs_in + (size_t)b * 131072;

  if (t < 64) {
    xto[t] = xt[a + t];
  } else if (t < 128) {
    int m = t - 64;
    int ns = (m < 32) ? (halfBase + m) : (1024 + halfBase + m - 32);
    xts[m] = xt[ns];
  }

  // ---- stage A1 = hs_src fp16 frags
  for (int i = t; i < 512; i += 256) {
    int m = i >> 3, k8 = i & 7;
    half8 v;
    if (first) {
#pragma unroll
      for (int e = 0; e < 8; ++e) v[e] = (_Float16)0.f;
    } else {
      int ns = (m < 32) ? (halfBase + m) : (1024 + halfBase + m - 32);
      v = *(const half8*)&hsb[(size_t)ns * 64 + k8 * 8];
    }
    int mt = m >> 4, ks = k8 >> 2, kc = k8 & 3;
    *(half8*)&A1f[(((mt * 2 + ks) * 64) + ((m & 15) | (kc << 4))) * 8] = v;
  }
  __syncthreads();

  // ---- Phase 1: ru = sigmoid(b1 + xt_src*w1_row0 + hs_src @ w1_rows1..64)
  {
    half8 B1[2][2];
#pragma unroll
    for (int q = 0; q < 2; ++q)
#pragma unroll
      for (int ks = 0; ks < 2; ++ks)
        B1[q][ks] = *(const half8*)&w1f[((((2 * wv + q) * 2 + ks) * 64) + l) * 8];
#pragma unroll
    for (int mt = 0; mt < 4; ++mt) {
      half8 Aa = *(half8*)&A1f[(((mt * 2 + 0) * 64) + l) * 8];
      half8 Ab = *(half8*)&A1f[(((mt * 2 + 1) * 64) + l) * 8];
      int r0 = mt * 16 + (l >> 4) * 4;
#pragma unroll
      for (int q = 0; q < 2; ++q) {
        int nt = 2 * wv + q;
        int col = nt * 16 + (l & 15);
        float bcol = b1[col], w1x = w1[col];
        f32x4 acc;
        acc[0] = bcol + xts[r0 + 0] * w1x;
        acc[1] = bcol + xts[r0 + 1] * w1x;
        acc[2] = bcol + xts[r0 + 2] * w1x;
        acc[3] = bcol + xts[r0 + 3] * w1x;
        acc = mfma16(Aa, B1[q][0], acc);
        acc = mfma16(Ab, B1[q][1], acc);
#pragma unroll
        for (int qq = 0; qq < 4; ++qq)
          ruF[ru_idx(r0 + qq, col)] = (_Float16)fast_sigmoid(acc[qq]);
      }
    }
  }
  __syncthreads();

  // ---- Phase 2a: A2f = r*hs frags; A1f = u*hs frags (A1f dead after P1)
  for (int i = t; i < 512; i += 256) {
    int n = i >> 3, k8 = i & 7;
    int c0 = ((n & 1) << 6) + k8 * 8;
    int base = afrag_idx(n, k8 * 8);   // 8-aligned (e=0)
    if (first) {
      half8 z;
#pragma unroll
      for (int e = 0; e < 8; ++e) z[e] = (_Float16)0.f;
      *(half8*)&A2f[base] = z;
      *(half8*)&A1f[base] = z;
    } else {
      half8 rv = *(half8*)&ruF[ru_idx(n >> 1, c0)];
      half8 uv = *(half8*)&ruF[ru_idx(32 + (n >> 1), c0)];
      half8 hv = *(const half8*)&hsb[(size_t)(a + n) * 64 + k8 * 8];
      half8 vr, vu;
#pragma unroll
      for (int e = 0; e < 8; ++e) {
        float hf = (float)hv[e];
        vr[e] = (_Float16)((float)rv[e] * hf);
        vu[e] = (_Float16)((float)uv[e] * hf);
      }
      *(half8*)&A2f[base] = vr;
      *(half8*)&A1f[base] = vu;
    }
  }
  __syncthreads();

  // ---- Phase 2b: c = tanh(...); fused: new = u*hs + (1-u)*c -> A1f frags
  {
    int nt = wv;
    half8 B2a = *(const half8*)&w2f[(((nt * 2 + 0) * 64) + l) * 8];
    half8 B2b = *(const half8*)&w2f[(((nt * 2 + 1) * 64) + l) * 8];
    int col = nt * 16 + (l & 15);
    float b2c = b2[col], w2x = w2[col];
#pragma unroll
    for (int mt = 0; mt < 4; ++mt) {
      half8 Aa = *(half8*)&A2f[(((mt * 2 + 0) * 64) + l) * 8];
      half8 Ab = *(half8*)&A2f[(((mt * 2 + 1) * 64) + l) * 8];
      int r0 = mt * 16 + (l >> 4) * 4;
      f32x4 acc;
      acc[0] = b2c + xto[r0 + 0] * w2x;
      acc[1] = b2c + xto[r0 + 1] * w2x;
      acc[2] = b2c + xto[r0 + 2] * w2x;
      acc[3] = b2c + xto[r0 + 3] * w2x;
      acc = mfma16(Aa, B2a, acc);
      acc = mfma16(Ab, B2b, acc);
#pragma unroll
      for (int qq = 0; qq < 4; ++qq) {
        int row = r0 + qq;
        float cv = fast_tanh(acc[qq]);
        float u = (float)ruF[ru_idx(32 + (row >> 1), ((row & 1) << 6) + col)];
        int idx3 = afrag_idx(row, col);
        float uh = (float)A1f[idx3];     // u*hs (0 when first)
        A1f[idx3] = (_Float16)(uh + (1.f - u) * cv);
      }
    }
  }
  __syncthreads();

  // ---- Phase 3b: out = fplC + new @ wlT
  {
    int nt = wv;
    half8 B3a = *(const half8*)&wlf[(((nt * 2 + 0) * 64) + l) * 8];
    half8 B3b = *(const half8*)&wlf[(((nt * 2 + 1) * 64) + l) * 8];
    int col = nt * 16 + (l & 15);
    const int tile = a >> 6;
#pragma unroll
    for (int mt = 0; mt < 4; ++mt) {
      half8 Aa = *(half8*)&A1f[(((mt * 2 + 0) * 64) + l) * 8];
      half8 Ab = *(half8*)&A1f[(((mt * 2 + 1) * 64) + l) * 8];
      int r0 = mt * 16 + (l >> 4) * 4;
      half4 f4 = *(const half4*)&fplC[(((tile * 4 + wv) * 256) + mt * 64 + l) * 4];
      f32x4 acc;
      acc[0] = (float)f4[0]; acc[1] = (float)f4[1];
      acc[2] = (float)f4[2]; acc[3] = (float)f4[3];
      acc = mfma16(Aa, B3a, acc);
      acc = mfma16(Ab, B3b, acc);
      if (outF32) {
        float* outp = (float*)hs_out_v;
#pragma unroll
        for (int qq = 0; qq < 4; ++qq)
          outp[(size_t)b * 131072 + (size_t)(a + r0 + qq) * 64 + col] = acc[qq];
      } else {
        _Float16* outp = (_Float16*)hs_out_v;
#pragma unroll
        for (int qq = 0; qq < 4; ++qq)
          outp[(size_t)b * 131072 + (size_t)(a + r0 + qq) * 64 + col] =
              (_Float16)acc[qq];
      }
    }
  }
}

// ---------------------------------------------------------------------------
extern "C" void kernel_launch(void* const* d_in, const int* in_sizes, int n_in,
                              void* d_out, int out_size, void* d_ws, size_t ws_size,
                              hipStream_t stream) {
  const float* h      = (const float*)d_in[0];
  const float* adj    = (const float*)d_in[1];
  const float* inputs = (const float*)d_in[2];
  const float* ew1    = (const float*)d_in[3];
  const float* eb1    = (const float*)d_in[4];
  const float* ew2    = (const float*)d_in[5];
  const float* eb2    = (const float*)d_in[6];
  const float* eps1   = (const float*)d_in[7];
  const float* bnw    = (const float*)d_in[8];
  const float* bnb    = (const float*)d_in[9];
  const float* w1     = (const float*)d_in[10];
  const float* b1     = (const float*)d_in[11];
  const float* w2     = (const float*)d_in[12];
  const float* b2     = (const float*)d_in[13];
  const float* wg     = (const float*)d_in[14];
  const float* bg     = (const float*)d_in[15];
  const float* wl_w   = (const float*)d_in[16];
  const float* wl_b   = (const float*)d_in[17];

  char* ws = (char*)d_ws;

  // ws layout (bytes):
  //  [0, 16777216)           h0 (fp16 hs ping)
  //  [16777216, 33554432)    h1 (fp16 hs pong)
  //    aliased pre-GRU inside h1: x1 (131072 f32), x2 (131072 f32),
  //      x1f (131072 f16), psum (4096 f32), pqsum (4096 f32),
  //      scale (64 f32), shift (64 f32)
  //  [33554432, +262144)     fplC (131072 halfs)
  //  then w1f (8192 halfs), w2f (4096), wlf (4096)
  _Float16* h0H = (_Float16*)ws;
  _Float16* h1H = (_Float16*)(ws + 16777216);
  float* x1    = (float*)h1H;
  float* x2    = x1 + 131072;
  _Float16* x1f = (_Float16*)(x2 + 131072);
  float* psum  = (float*)(x1f + 131072);
  float* pqsum = psum + 4096;
  float* scale = pqsum + 4096;
  float* shift = scale + 64;
  _Float16* fplC = (_Float16*)(ws + 33554432);
  _Float16* w1f  = fplC + 131072;
  _Float16* w2f  = w1f + 8192;
  _Float16* wlf  = w2f + 4096;

  extract1<<<512, 256, 0, stream>>>(h, ew1, eb1, x1, x1f);
  extract2_mfma<<<256, 256, 0, stream>>>(adj, x1, x1f, eps1, x2);
  extract3a<<<64, 256, 0, stream>>>(x2, psum, pqsum);
  extract3b<<<1, 64, 0, stream>>>(psum, pqsum, bnw, bnb, scale, shift);
  extract4<<<512, 256, 0, stream>>>(x2, scale, shift, ew2, eb2, wg, bg,
                                    wl_w, wl_b, fplC);
  prep_frags<<<64, 256, 0, stream>>>(w1, w2, wl_w, w1f, w2f, wlf);

  dim3 grid(32, 64);
  for (int t = 0; t < 12; ++t) {
    const _Float16* ibuf = (t & 1) ? h0H : h1H;   // t=0 ignores (first=1)
    void* obuf; int of32 = 0;
    if (t == 11) { obuf = d_out; of32 = 1; }
    else obuf = (t & 1) ? (void*)h1H : (void*)h0H;
    gru_step<<<grid, 256, 0, stream>>>(ibuf, obuf, of32, inputs, t,
                                       (t == 0) ? 1 : 0,
                                       w1, b1, w2, b2, fplC, w1f, w2f, wlf);
  }
}

// Round 6
// 298.567 us; speedup vs baseline: 6.4852x; 1.0487x over previous
//
#include <hip/hip_runtime.h>
#include <cstdint>

// Problem dims: N=2048, IN_DIM=128, HID=64, ENC=64, B=64, SEQ=12

typedef _Float16 half8 __attribute__((ext_vector_type(8)));
typedef _Float16 half4 __attribute__((ext_vector_type(4)));
typedef float f32x4 __attribute__((ext_vector_type(4)));

static __device__ inline f32x4 mfma16(half8 a, half8 b, f32x4 c) {
  return __builtin_amdgcn_mfma_f32_16x16x32_f16(a, b, c, 0, 0, 0);
}

static __device__ inline float fast_sigmoid(float x) {
  return __builtin_amdgcn_rcpf(1.f + __expf(-x));
}
static __device__ inline float fast_tanh(float x) {
  return 1.f - 2.f * __builtin_amdgcn_rcpf(__expf(2.f * x) + 1.f);
}

// A-fragment slot (element n,k) -> half index in a 4096-half fragment buffer
static __device__ inline int afrag_idx(int n, int k) {
  return ((((n >> 4) * 2 + (k >> 5)) * 64) + ((n & 15) | (((k >> 3) & 3) << 4))) * 8
         + (k & 7);
}

// ---------------------------------------------------------------------------
// E1 fused: x1[n,j] = eb1[j] + sum_k h[n,k]*ew1[j,k]; also x1f frag (fp16)
__global__ __launch_bounds__(256) void extract1(
    const float* __restrict__ h, const float* __restrict__ ew1,
    const float* __restrict__ eb1, float* __restrict__ x1,
    _Float16* __restrict__ x1f)
{
  int idx = blockIdx.x * 256 + threadIdx.x;   // 131072 total
  int n = idx >> 6, j = idx & 63;
  const float4* hr = (const float4*)(h + (size_t)n * 128);
  const float4* wr = (const float4*)(ew1 + (size_t)j * 128);
  float acc = eb1[j];
#pragma unroll
  for (int k4 = 0; k4 < 32; ++k4) {
    float4 a = hr[k4], w = wr[k4];
    acc += a.x * w.x + a.y * w.y + a.z * w.z + a.w * w.w;
  }
  x1[idx] = acc;
  // B-frag slot for (k=n, col=j): ks=n>>5, nt=j>>4, l=(j&15)|(((n>>3)&3)<<4), e=n&7
  int ks = n >> 5, nt = j >> 4;
  int l = (j & 15) | (((n >> 3) & 3) << 4);
  x1f[(((ks * 4 + nt) * 64) + l) * 8 + (n & 7)] = (_Float16)acc;
}

// ---------------------------------------------------------------------------
// E2 (MFMA): pooled = adj @ x1 (fp16 frags), deg = rowsum(adj) fp32;
//            x2 = pooled/deg + eps1*x1
__global__ __launch_bounds__(256) void extract2_mfma(
    const float* __restrict__ adj, const float* __restrict__ x1,
    const _Float16* __restrict__ x1f, const float* __restrict__ eps1,
    float* __restrict__ x2)
{
  const int n0 = blockIdx.x * 8;
  const int t = threadIdx.x;
  const int l = t & 63, wv = t >> 6;
  __shared__ __align__(16) _Float16 Abuf[4096];
  __shared__ float deg_l[8];

  for (int i = t; i < 4096; i += 256) Abuf[i] = (_Float16)0.f;

  const int row = t >> 5;
  const int kcol = (t & 31) * 8;
  const int s_my = (t & 31) >> 2;
  const int c_my = t & 3;

  float degp = 0.f;
  f32x4 acc = {0.f, 0.f, 0.f, 0.f};

  for (int kc = 0; kc < 8; ++kc) {
    __syncthreads();
    {
      const float* src = &adj[(size_t)(n0 + row) * 2048 + kc * 256 + kcol];
      float4 p0 = *(const float4*)src;
      float4 p1 = *(const float4*)(src + 4);
      degp += p0.x + p0.y + p0.z + p0.w + p1.x + p1.y + p1.z + p1.w;
      half8 v;
      v[0] = (_Float16)p0.x; v[1] = (_Float16)p0.y;
      v[2] = (_Float16)p0.z; v[3] = (_Float16)p0.w;
      v[4] = (_Float16)p1.x; v[5] = (_Float16)p1.y;
      v[6] = (_Float16)p1.z; v[7] = (_Float16)p1.w;
      *(half8*)&Abuf[(size_t)(s_my * 64 + (row | (c_my << 4))) * 8] = v;
    }
    __syncthreads();
#pragma unroll
    for (int s = 0; s < 8; ++s) {
      half8 A = *(half8*)&Abuf[(s * 64 + l) * 8];
      half8 B = *(const half8*)&x1f[(size_t)(((kc * 8 + s) * 4 + wv) * 64 + l) * 8];
      acc = mfma16(A, B, acc);
    }
  }

  for (int sh = 16; sh >= 1; sh >>= 1) degp += __shfl_down(degp, sh, 32);
  if ((t & 31) == 0) deg_l[row] = degp;
  __syncthreads();

  const float ep = eps1[0];
  int colc = wv * 16 + (l & 15);
  int r0 = (l >> 4) * 4;
  if (r0 < 8) {
#pragma unroll
    for (int q = 0; q < 4; ++q) {
      int r = r0 + q;
      float d = deg_l[r];
      d = (d < 1e-6f) ? 1.f : d;
      size_t off = (size_t)(n0 + r) * 64 + colc;
      x2[off] = acc[q] / d + ep * x1[off];
    }
  }
}

// ---------------------------------------------------------------------------
// E3a: partial BN sums over 32-row stripes -> psum/pqsum[64][64]
__global__ __launch_bounds__(256) void extract3a(
    const float* __restrict__ x2, float* __restrict__ psum,
    float* __restrict__ pqsum)
{
  int g = blockIdx.x;
  int t = threadIdx.x, j = t & 63, rg = t >> 6;
  __shared__ float sl[4][64], ql[4][64];
  float s = 0.f, q = 0.f;
  for (int r = g * 32 + rg; r < g * 32 + 32; r += 4) {
    float v = x2[(size_t)r * 64 + j];
    s += v; q += v * v;
  }
  sl[rg][j] = s; ql[rg][j] = q;
  __syncthreads();
  if (t < 64) {
    psum[g * 64 + t]  = sl[0][t] + sl[1][t] + sl[2][t] + sl[3][t];
    pqsum[g * 64 + t] = ql[0][t] + ql[1][t] + ql[2][t] + ql[3][t];
  }
}

__global__ void extract3b(
    const float* __restrict__ psum, const float* __restrict__ pqsum,
    const float* __restrict__ bnw, const float* __restrict__ bnb,
    float* __restrict__ scale, float* __restrict__ shift)
{
  int j = threadIdx.x;   // 64 threads
  float s = 0.f, q = 0.f;
  for (int g = 0; g < 64; ++g) { s += psum[g * 64 + j]; q += pqsum[g * 64 + j]; }
  float mean = s * (1.f / 2048.f);
  float var = q * (1.f / 2048.f) - mean * mean;
  float rstd = rsqrtf(var + 1e-5f);
  float sc = rstd * bnw[j];
  scale[j] = sc;
  shift[j] = bnb[j] - mean * sc;
}

// ---------------------------------------------------------------------------
// E4: xn = x2*scale+shift; feat = xn@ew2.T+eb2; fp = feat@wg+bg;
//     fplC (C-fragment layout, fp16)
__global__ __launch_bounds__(256) void extract4(
    const float* __restrict__ x2, const float* __restrict__ scale,
    const float* __restrict__ shift, const float* __restrict__ ew2,
    const float* __restrict__ eb2, const float* __restrict__ wg,
    const float* __restrict__ bg, const float* __restrict__ wl_w,
    const float* __restrict__ wl_b, _Float16* __restrict__ fplC)
{
  __shared__ float xn[4][64], ft[4][64], fp[4][64];
  int t = threadIdx.x, sub = t >> 6, o = t & 63;
  int n = blockIdx.x * 4 + sub;
  xn[sub][o] = x2[(size_t)n * 64 + o] * scale[o] + shift[o];
  __syncthreads();
  {
    float acc = eb2[o];
    for (int k = 0; k < 64; ++k) acc += xn[sub][k] * ew2[o * 64 + k];
    ft[sub][o] = acc;
  }
  __syncthreads();
  {
    float acc = bg[0];
    for (int k = 0; k < 64; ++k) acc += ft[sub][k] * wg[k * 64 + o];
    fp[sub][o] = acc;
  }
  __syncthreads();
  {
    float acc = wl_b[o];
    for (int k = 0; k < 64; ++k) acc += fp[sub][k] * wl_w[o * 128 + 64 + k];
    int tile = n >> 6, r = n & 63;
    int mt = r >> 4, qq = r & 3;
    int l = (o & 15) | (((r >> 2) & 3) << 4);
    fplC[(((tile * 4 + (o >> 4)) * 256) + mt * 64 + l) * 4 + qq] = (_Float16)acc;
  }
}

// ---------------------------------------------------------------------------
// Weight -> fp16 fragment arrays (k-map: kk = (l>>4)*8 + e).
__global__ __launch_bounds__(256) void prep_frags(
    const float* __restrict__ w1, const float* __restrict__ w2,
    const float* __restrict__ wl_w, _Float16* __restrict__ w1f,
    _Float16* __restrict__ w2f, _Float16* __restrict__ wlf)
{
  int idx = blockIdx.x * 256 + threadIdx.x;   // 16384 total
  int e = idx & 7, l = (idx >> 3) & 63;
  int kk = ((l >> 4) * 8) + e;
  if (idx < 8192) {
    int ks = (idx >> 9) & 1, nt = idx >> 10;  // nt 0..7
    int k = ks * 32 + kk;
    w1f[idx] = (_Float16)w1[(1 + k) * 128 + nt * 16 + (l & 15)];
  } else if (idx < 12288) {
    int i2 = idx - 8192;
    int ks = (i2 >> 9) & 1, nt = i2 >> 10;    // nt 0..3
    int k = ks * 32 + kk;
    w2f[i2] = (_Float16)w2[(1 + k) * 64 + nt * 16 + (l & 15)];
  } else {
    int i3 = idx - 12288;
    int ks = (i3 >> 9) & 1, nt = i3 >> 10;    // nt 0..3
    int k = ks * 32 + kk;
    wlf[i3] = (_Float16)wl_w[(nt * 16 + (l & 15)) * 128 + k];
  }
}

// ---------------------------------------------------------------------------
// One GRU step, fp16 MFMA, fp16 hs state, 3-barrier structure.
// Block: batch b (blockIdx.y), nodes [a, a+64). 256 threads = 4 waves.
// P1 epilogue fuses the old P2a: gate (src-row m, col j2) maps to consumer
// element (n = 2m + (j2>=64), k = j2&63); j2>=64 is wave-uniform (wv>=2).
__global__ __launch_bounds__(256, 4) void gru_step(
    const _Float16* __restrict__ hs_in, void* __restrict__ hs_out_v,
    int outF32, const float* __restrict__ inputs, int tstep, int first,
    const float* __restrict__ w1, const float* __restrict__ b1,
    const float* __restrict__ w2, const float* __restrict__ b2,
    const _Float16* __restrict__ fplC, const _Float16* __restrict__ w1f,
    const _Float16* __restrict__ w2f, const _Float16* __restrict__ wlf)
{
  const int b = blockIdx.y;
  const int a = blockIdx.x * 64;
  const int t = threadIdx.x;
  const int l = t & 63, wv = t >> 6;
  const int halfBase = a >> 1;

  __shared__ __align__(16) _Float16 Asrc[4096];   // hs_src frags; reused as A3 (new)
  __shared__ __align__(16) _Float16 A2f[4096];    // rh frags
  __shared__ __align__(16) _Float16 uF[4096];     // u gates (afrag layout)
  __shared__ __align__(16) _Float16 hsOwn[4096];  // own hs rows [64][64]
  __shared__ float xts[64], xto[64];

  const float* xt  = inputs + (size_t)(b * 12 + tstep) * 2048;
  const _Float16* hsb = hs_in + (size_t)b * 131072;

  if (t < 64) {
    xto[t] = xt[a + t];
  } else if (t < 128) {
    int m = t - 64;
    int ns = (m < 32) ? (halfBase + m) : (1024 + halfBase + m - 32);
    xts[m] = xt[ns];
  }

  // ---- stage hsOwn (coalesced) + Asrc = hs_src fp16 frags
  for (int i = t; i < 512; i += 256) {
    half8 v;
    if (first) {
#pragma unroll
      for (int e = 0; e < 8; ++e) v[e] = (_Float16)0.f;
    } else {
      v = *(const half8*)&hsb[(size_t)(a + (i >> 3)) * 64 + (i & 7) * 8];
    }
    *(half8*)&hsOwn[i * 8] = v;
  }
  for (int i = t; i < 512; i += 256) {
    int m = i >> 3, k8 = i & 7;
    half8 v;
    if (first) {
#pragma unroll
      for (int e = 0; e < 8; ++e) v[e] = (_Float16)0.f;
    } else {
      int ns = (m < 32) ? (halfBase + m) : (1024 + halfBase + m - 32);
      v = *(const half8*)&hsb[(size_t)ns * 64 + k8 * 8];
    }
    int mt = m >> 4, ks = k8 >> 2, kc = k8 & 3;
    *(half8*)&Asrc[(((mt * 2 + ks) * 64) + ((m & 15) | (kc << 4))) * 8] = v;
  }

  // ---- prefetch fplC C-frags (held in regs across all phases)
  half4 fpl[4];
  {
    const int tile = a >> 6;
#pragma unroll
    for (int mt = 0; mt < 4; ++mt)
      fpl[mt] = *(const half4*)&fplC[(((tile * 4 + wv) * 256) + mt * 64 + l) * 4];
  }
  __syncthreads();

  // ---- Phase 1: gates = sigmoid(b1 + xt_src*w1_row0 + hs_src @ w1_rows1..64)
  //      fused scatter: r-part -> A2f = r*hsOwn; u-part -> uF = u
  {
    half8 B1[2][2];
#pragma unroll
    for (int q = 0; q < 2; ++q)
#pragma unroll
      for (int ks = 0; ks < 2; ++ks)
        B1[q][ks] = *(const half8*)&w1f[((((2 * wv + q) * 2 + ks) * 64) + l) * 8];
    const int bit = (wv >> 1);   // j2>=64 iff wv>=2
#pragma unroll
    for (int mt = 0; mt < 4; ++mt) {
      half8 Aa = *(half8*)&Asrc[(((mt * 2 + 0) * 64) + l) * 8];
      half8 Ab = *(half8*)&Asrc[(((mt * 2 + 1) * 64) + l) * 8];
      int r0 = mt * 16 + (l >> 4) * 4;
#pragma unroll
      for (int q = 0; q < 2; ++q) {
        int nt = 2 * wv + q;
        int col = nt * 16 + (l & 15);
        float bcol = b1[col], w1x = w1[col];
        f32x4 acc;
        acc[0] = bcol + xts[r0 + 0] * w1x;
        acc[1] = bcol + xts[r0 + 1] * w1x;
        acc[2] = bcol + xts[r0 + 2] * w1x;
        acc[3] = bcol + xts[r0 + 3] * w1x;
        acc = mfma16(Aa, B1[q][0], acc);
        acc = mfma16(Ab, B1[q][1], acc);
        const int k = col & 63;
#pragma unroll
        for (int qq = 0; qq < 4; ++qq) {
          float g = fast_sigmoid(acc[qq]);
          int m = r0 + qq;
          if (mt < 2) {          // r rows (m < 32)
            int n = 2 * m + bit;
            float hf = (float)hsOwn[n * 64 + k];
            A2f[afrag_idx(n, k)] = (_Float16)(g * hf);
          } else {               // u rows (m >= 32)
            int n = 2 * (m - 32) + bit;
            uF[afrag_idx(n, k)] = (_Float16)g;
          }
        }
      }
    }
  }
  __syncthreads();

  // ---- Phase 2: c = tanh(b2 + xt_own*w2_row0 + rh @ w2_rows1..64)
  //      fused: new = u*hsOwn + (1-u)*c -> Asrc (dead after P1)
  {
    int nt = wv;
    half8 B2a = *(const half8*)&w2f[(((nt * 2 + 0) * 64) + l) * 8];
    half8 B2b = *(const half8*)&w2f[(((nt * 2 + 1) * 64) + l) * 8];
    int col = nt * 16 + (l & 15);
    float b2c = b2[col], w2x = w2[col];
#pragma unroll
    for (int mt = 0; mt < 4; ++mt) {
      half8 Aa = *(half8*)&A2f[(((mt * 2 + 0) * 64) + l) * 8];
      half8 Ab = *(half8*)&A2f[(((mt * 2 + 1) * 64) + l) * 8];
      int r0 = mt * 16 + (l >> 4) * 4;
      f32x4 acc;
      acc[0] = b2c + xto[r0 + 0] * w2x;
      acc[1] = b2c + xto[r0 + 1] * w2x;
      acc[2] = b2c + xto[r0 + 2] * w2x;
      acc[3] = b2c + xto[r0 + 3] * w2x;
      acc = mfma16(Aa, B2a, acc);
      acc = mfma16(Ab, B2b, acc);
#pragma unroll
      for (int qq = 0; qq < 4; ++qq) {
        int row = r0 + qq;
        float cv = fast_tanh(acc[qq]);
        int idx3 = afrag_idx(row, col);
        float u = (float)uF[idx3];
        float hsv = (float)hsOwn[row * 64 + col];
        Asrc[idx3] = (_Float16)(u * hsv + (1.f - u) * cv);
      }
    }
  }
  __syncthreads();

  // ---- Phase 3: out = fplC + new @ wlT
  {
    int nt = wv;
    half8 B3a = *(const half8*)&wlf[(((nt * 2 + 0) * 64) + l) * 8];
    half8 B3b = *(const half8*)&wlf[(((nt * 2 + 1) * 64) + l) * 8];
    int col = nt * 16 + (l & 15);
#pragma unroll
    for (int mt = 0; mt < 4; ++mt) {
      half8 Aa = *(half8*)&Asrc[(((mt * 2 + 0) * 64) + l) * 8];
      half8 Ab = *(half8*)&Asrc[(((mt * 2 + 1) * 64) + l) * 8];
      int r0 = mt * 16 + (l >> 4) * 4;
      f32x4 acc;
      acc[0] = (float)fpl[mt][0]; acc[1] = (float)fpl[mt][1];
      acc[2] = (float)fpl[mt][2]; acc[3] = (float)fpl[mt][3];
      acc = mfma16(Aa, B3a, acc);
      acc = mfma16(Ab, B3b, acc);
      if (outF32) {
        float* outp = (float*)hs_out_v;
#pragma unroll
        for (int qq = 0; qq < 4; ++qq)
          outp[(size_t)b * 131072 + (size_t)(a + r0 + qq) * 64 + col] = acc[qq];
      } else {
        _Float16* outp = (_Float16*)hs_out_v;
#pragma unroll
        for (int qq = 0; qq < 4; ++qq)
          outp[(size_t)b * 131072 + (size_t)(a + r0 + qq) * 64 + col] =
              (_Float16)acc[qq];
      }
    }
  }
}

// ---------------------------------------------------------------------------
extern "C" void kernel_launch(void* const* d_in, const int* in_sizes, int n_in,
                              void* d_out, int out_size, void* d_ws, size_t ws_size,
                              hipStream_t stream) {
  const float* h      = (const float*)d_in[0];
  const float* adj    = (const float*)d_in[1];
  const float* inputs = (const float*)d_in[2];
  const float* ew1    = (const float*)d_in[3];
  const float* eb1    = (const float*)d_in[4];
  const float* ew2    = (const float*)d_in[5];
  const float* eb2    = (const float*)d_in[6];
  const float* eps1   = (const float*)d_in[7];
  const float* bnw    = (const float*)d_in[8];
  const float* bnb    = (const float*)d_in[9];
  const float* w1     = (const float*)d_in[10];
  const float* b1     = (const float*)d_in[11];
  const float* w2     = (const float*)d_in[12];
  const float* b2     = (const float*)d_in[13];
  const float* wg     = (const float*)d_in[14];
  const float* bg     = (const float*)d_in[15];
  const float* wl_w   = (const float*)d_in[16];
  const float* wl_b   = (const float*)d_in[17];

  char* ws = (char*)d_ws;

  // ws layout (bytes):
  //  [0, 16777216)           h0 (fp16 hs ping)
  //  [16777216, 33554432)    h1 (fp16 hs pong)
  //    aliased pre-GRU inside h1: x1 (131072 f32), x2 (131072 f32),
  //      x1f (131072 f16), psum (4096 f32), pqsum (4096 f32),
  //      scale (64 f32), shift (64 f32)
  //  [33554432, +262144)     fplC (131072 halfs)
  //  then w1f (8192 halfs), w2f (4096), wlf (4096)
  _Float16* h0H = (_Float16*)ws;
  _Float16* h1H = (_Float16*)(ws + 16777216);
  float* x1    = (float*)h1H;
  float* x2    = x1 + 131072;
  _Float16* x1f = (_Float16*)(x2 + 131072);
  float* psum  = (float*)(x1f + 131072);
  float* pqsum = psum + 4096;
  float* scale = pqsum + 4096;
  float* shift = scale + 64;
  _Float16* fplC = (_Float16*)(ws + 33554432);
  _Float16* w1f  = fplC + 131072;
  _Float16* w2f  = w1f + 8192;
  _Float16* wlf  = w2f + 4096;

  extract1<<<512, 256, 0, stream>>>(h, ew1, eb1, x1, x1f);
  extract2_mfma<<<256, 256, 0, stream>>>(adj, x1, x1f, eps1, x2);
  extract3a<<<64, 256, 0, stream>>>(x2, psum, pqsum);
  extract3b<<<1, 64, 0, stream>>>(psum, pqsum, bnw, bnb, scale, shift);
  extract4<<<512, 256, 0, stream>>>(x2, scale, shift, ew2, eb2, wg, bg,
                                    wl_w, wl_b, fplC);
  prep_frags<<<64, 256, 0, stream>>>(w1, w2, wl_w, w1f, w2f, wlf);

  dim3 grid(32, 64);
  for (int t = 0; t < 12; ++t) {
    const _Float16* ibuf = (t & 1) ? h0H : h1H;   // t=0 ignores (first=1)
    void* obuf; int of32 = 0;
    if (t == 11) { obuf = d_out; of32 = 1; }
    else obuf = (t & 1) ? (void*)h1H : (void*)h0H;
    gru_step<<<grid, 256, 0, stream>>>(ibuf, obuf, of32, inputs, t,
                                       (t == 0) ? 1 : 0,
                                       w1, b1, w2, b2, fplC, w1f, w2f, wlf);
  }
}